// Round 5
// baseline (297.395 us; speedup 1.0000x reference)
//
#include <hip/hip_runtime.h>
#include <hip/hip_bf16.h>
#include <math.h>

#define NEG_SLOPE 0.2f
#define LN_EPS 1e-5f

constexpr int B = 64, A = 256, L = 1024, D = 128;

typedef float f32x4 __attribute__((ext_vector_type(4)));
typedef short bf16x8 __attribute__((ext_vector_type(8)));

__device__ __forceinline__ ushort f2bf(float x) {
    __hip_bfloat16 h = __float2bfloat16(x);
    return *reinterpret_cast<ushort*>(&h);
}
// monotone float<->uint keys for atomicMax on floats
__device__ __forceinline__ unsigned fkey(float f) {
    int i = __float_as_int(f);
    return (i >= 0) ? ((unsigned)i | 0x80000000u) : ~(unsigned)i;
}
__device__ __forceinline__ float fdecode(unsigned u) {
    int i = (u & 0x80000000u) ? (int)(u & 0x7fffffffu) : ~(int)u;
    return __int_as_float(i);
}

// ---------------------------------------------------------------------------
// prep: u = W_mol @ w_align_mol ; c0 = b_mol.w_align_mol + b_align ;
//       WT[d][e] = bf16(W_nb[e][d]) ; zero-init Mmax keys
// ---------------------------------------------------------------------------
__global__ void prep_kernel(const float* __restrict__ Wmol, const float* __restrict__ bmol,
                            const float* __restrict__ wam, const float* __restrict__ bal,
                            const float* __restrict__ Wnb,
                            float* __restrict__ u, float* __restrict__ c0,
                            ushort* __restrict__ WT, unsigned* __restrict__ Mmax) {
    __shared__ float red[2], red2[2];
    const int d = blockIdx.x, e = threadIdx.x;   // 128 blocks x 128 threads
    const int lane = e & 63, wv = e >> 6;
    if (d == 1 && e < 64) Mmax[e] = 0u;          // key 0 == most negative float
    float p = Wmol[d * D + e] * wam[e];
    #pragma unroll
    for (int o = 1; o < 64; o <<= 1) p += __shfl_xor(p, o);
    WT[d * D + e] = f2bf(Wnb[e * D + d]);
    float q = 0.f;
    if (d == 0) q = bmol[e] * wam[e];
    #pragma unroll
    for (int o = 1; o < 64; o <<= 1) q += __shfl_xor(q, o);
    if (lane == 0) { red[wv] = p; red2[wv] = q; }
    __syncthreads();
    if (e == 0) {
        u[d] = red[0] + red[1];
        if (d == 0) c0[0] = red2[0] + red2[1] + bal[0];
    }
}

// ---------------------------------------------------------------------------
// nb_gemm: 2048 blocks x 128 thr, 32 l-rows per block, MFMA, fp32 epilogue.
// Adds per-batch masked-max of s_atm via atomicMax(key).
// ---------------------------------------------------------------------------
__global__ __launch_bounds__(128, 4) void nb_gemm_kernel(
    const float* __restrict__ atom, const ushort* __restrict__ WT,
    const float* __restrict__ bias, const float* __restrict__ wa,
    const float* __restrict__ smask,
    ushort* __restrict__ atmT, float* __restrict__ s_atmM,
    float* __restrict__ e_l, float* __restrict__ f_l,
    unsigned* __restrict__ Mmax) {
    __shared__ ushort tb[128][36];   // [d][l-local], padded
    const int tid = threadIdx.x;
    const int wv = tid >> 6, lane = tid & 63, la = lane & 15, kg = lane >> 4;
    const int R0 = blockIdx.x * 32;
    const int b = R0 >> 10, l0 = R0 & 1023;
    const int row = R0 + wv * 16 + la;

    const float* arow = atom + (size_t)row * D + kg * 8;
    bf16x8 af[4];
    #pragma unroll
    for (int ks = 0; ks < 4; ++ks) {
        float4 x0 = *(const float4*)&arow[ks * 32];
        float4 x1 = *(const float4*)&arow[ks * 32 + 4];
        bf16x8 t;
        t[0] = (short)f2bf(x0.x); t[1] = (short)f2bf(x0.y);
        t[2] = (short)f2bf(x0.z); t[3] = (short)f2bf(x0.w);
        t[4] = (short)f2bf(x1.x); t[5] = (short)f2bf(x1.y);
        t[6] = (short)f2bf(x1.z); t[7] = (short)f2bf(x1.w);
        af[ks] = t;
    }
    float wav[8], bv[8];
    #pragma unroll
    for (int dt = 0; dt < 8; ++dt) { wav[dt] = wa[dt * 16 + la]; bv[dt] = bias[dt * 16 + la]; }

    f32x4 acc[8];
    #pragma unroll
    for (int dt = 0; dt < 8; ++dt) acc[dt] = (f32x4){bv[dt], bv[dt], bv[dt], bv[dt]};
    #pragma unroll
    for (int ks = 0; ks < 4; ++ks) {
        #pragma unroll
        for (int dt = 0; dt < 8; ++dt) {
            bf16x8 bf = *(const bf16x8*)&WT[(size_t)(dt * 16 + la) * D + ks * 32 + kg * 8];
            acc[dt] = __builtin_amdgcn_mfma_f32_16x16x32_bf16(af[ks], bf, acc[dt], 0, 0, 0);
        }
    }

    float sr[4];
    #pragma unroll
    for (int r = 0; r < 4; ++r) {
        float t = 0.f;
        #pragma unroll
        for (int dt = 0; dt < 8; ++dt) t += acc[dt][r] * wav[dt];
        t += __shfl_xor(t, 1); t += __shfl_xor(t, 2);
        t += __shfl_xor(t, 4); t += __shfl_xor(t, 8);
        sr[r] = t;
    }
    float mloc = -3.0e38f;
    if (la == 0) {
        #pragma unroll
        for (int r = 0; r < 4; ++r) {
            int l = l0 + wv * 16 + kg * 4 + r;
            float sm = smask[(size_t)b * L + l];
            bool val = sm > -0.5f;
            float sv = sr[r];
            float svm = val ? sv : -1e30f;
            s_atmM[(size_t)b * L + l] = svm;
            e_l[(size_t)b * L + l]    = val ? __expf(sv) : 0.f;
            f_l[(size_t)b * L + l]    = val ? __expf(NEG_SLOPE * sv) : 0.f;
            mloc = fmaxf(mloc, svm);
        }
    }
    #pragma unroll
    for (int o = 1; o < 64; o <<= 1) mloc = fmaxf(mloc, __shfl_xor(mloc, o));
    if (lane == 0) atomicMax(&Mmax[b], fkey(mloc));

    #pragma unroll
    for (int dt = 0; dt < 8; ++dt) {
        union { ushort us[4]; uint2 v; } pk;
        #pragma unroll
        for (int r = 0; r < 4; ++r) pk.us[r] = f2bf(acc[dt][r]);
        *(uint2*)&tb[dt * 16 + la][wv * 16 + kg * 4] = pk.v;
    }
    __syncthreads();
    {
        const int c = tid & 3, dd = tid >> 2;
        #pragma unroll
        for (int j = 0; j < 4; ++j) {
            int d = dd + j * 32;
            *(int4*)&atmT[((size_t)(b * 128 + d) << 10) + l0 + c * 8] =
                *(const int4*)&tb[d][c * 8];
        }
    }
}

// ---------------------------------------------------------------------------
// attn v6: block = (b, 16 a-rows), 4 waves; wave w owns d-slice [32w,32w+32)
// over FULL L. 4-deep register prefetch of atmT fragments, no main-loop
// barriers, redundant bfrag per wave, per-wave-complete ctx -> tiny LN
// exchange. One barrier before main loop, one before LN.
// ---------------------------------------------------------------------------
__global__ __launch_bounds__(256, 4) void attn_kernel(
    const float* __restrict__ molf, const float* __restrict__ amask,
    const ushort* __restrict__ atmT,
    const float* __restrict__ s_atmM_g, const float* __restrict__ e_lG,
    const float* __restrict__ f_lG,
    const float* __restrict__ u, const float* __restrict__ c0p,
    const unsigned* __restrict__ Mmax,
    const float* __restrict__ gamma, const float* __restrict__ beta,
    float* __restrict__ out) {
    __shared__ float sL[L], eL[L], fL[L];          // 12 KB tables
    __shared__ float thL[16], eaL[16], faL[16];
    __shared__ float gbL[256];
    __shared__ float lnP[4][16][2];

    const int bid = blockIdx.x;
    const int lid = (bid & 7) * 128 + (bid >> 3);  // XCD-bijective (1024 % 8 == 0)
    const int b  = lid >> 4;
    const int at = lid & 15;
    const int tid = threadIdx.x;
    const int w = tid >> 6, lane = tid & 63;
    const int la = lane & 15, kg = lane >> 4;

    // ---- prologue: issue first 4 iterations' A-fragment loads ----
    const ushort* atmTb = atmT + (size_t)b * D * L;
    const size_t r0 = (size_t)(w * 32 + la) * L;        // t=0 row
    const size_t r1 = (size_t)(w * 32 + 16 + la) * L;   // t=1 row
    bf16x8 af[4][2];
    #pragma unroll
    for (int i = 0; i < 4; ++i) {
        af[i][0] = *(const bf16x8*)&atmTb[r0 + i * 32 + kg * 8];
        af[i][1] = *(const bf16x8*)&atmTb[r1 + i * 32 + kg * 8];
    }

    // ---- phase 1: tables + gamma/beta ----
    {
        int i4 = tid * 4;
        *(float4*)&sL[i4] = *(const float4*)&s_atmM_g[(size_t)b * L + i4];
        *(float4*)&eL[i4] = *(const float4*)&e_lG[(size_t)b * L + i4];
        *(float4*)&fL[i4] = *(const float4*)&f_lG[(size_t)b * L + i4];
        if (tid < 32)      ((float4*)gbL)[tid] = ((const float4*)gamma)[tid];
        else if (tid < 64) ((float4*)gbL)[tid] = ((const float4*)beta)[tid - 32];
    }
    // ---- phase 2: s_mol + per-row softmax constants ----
    {
        float M = fdecode(Mmax[b]);
        int r = tid >> 4, q = tid & 15;
        const float* x = molf + ((size_t)b * A + at * 16 + r) * D + q * 8;
        float4 xa = *(const float4*)x;
        float4 xb = *(const float4*)(x + 4);
        float4 ua = *(const float4*)&u[q * 8];
        float4 ub = *(const float4*)&u[q * 8 + 4];
        float p = xa.x * ua.x + xa.y * ua.y + xa.z * ua.z + xa.w * ua.w
                + xb.x * ub.x + xb.y * ub.y + xb.z * ub.z + xb.w * ub.w;
        p += __shfl_xor(p, 1); p += __shfl_xor(p, 2);
        p += __shfl_xor(p, 4); p += __shfl_xor(p, 8);
        if (q == 0) {
            float sm = p + c0p[0];
            float z = sm + M;
            float m = (z > 0.f) ? z : NEG_SLOPE * z;   // exact row max
            thL[r] = -sm;
            eaL[r] = __expf(sm - m);
            faL[r] = __expf(NEG_SLOPE * sm - m);
        }
    }
    __syncthreads();

    const float ea = eaL[la], fa = faL[la], th = thL[la];
    f32x4 acc0 = {}, acc1 = {};
    float psum = 0.f;
    bf16x8 pf[2];

#define BFRAG(DST, I)                                                          \
    {                                                                          \
        const int lb_ = (I) * 32 + kg * 8;                                     \
        float4 s0 = *(const float4*)&sL[lb_];                                  \
        float4 s1 = *(const float4*)&sL[lb_ + 4];                              \
        float4 e0 = *(const float4*)&eL[lb_];                                  \
        float4 e1 = *(const float4*)&eL[lb_ + 4];                              \
        float4 f0 = *(const float4*)&fL[lb_];                                  \
        float4 f1 = *(const float4*)&fL[lb_ + 4];                              \
        float p0 = (s0.x > th) ? ea * e0.x : fa * f0.x;                        \
        float p1 = (s0.y > th) ? ea * e0.y : fa * f0.y;                        \
        float p2 = (s0.z > th) ? ea * e0.z : fa * f0.z;                        \
        float p3 = (s0.w > th) ? ea * e0.w : fa * f0.w;                        \
        float p4 = (s1.x > th) ? ea * e1.x : fa * f1.x;                        \
        float p5 = (s1.y > th) ? ea * e1.y : fa * f1.y;                        \
        float p6 = (s1.z > th) ? ea * e1.z : fa * f1.z;                        \
        float p7 = (s1.w > th) ? ea * e1.w : fa * f1.w;                        \
        psum += (p0 + p1) + (p2 + p3) + ((p4 + p5) + (p6 + p7));               \
        DST[0] = (short)f2bf(p0); DST[1] = (short)f2bf(p1);                    \
        DST[2] = (short)f2bf(p2); DST[3] = (short)f2bf(p3);                    \
        DST[4] = (short)f2bf(p4); DST[5] = (short)f2bf(p5);                    \
        DST[6] = (short)f2bf(p6); DST[7] = (short)f2bf(p7);                    \
    }

    BFRAG(pf[0], 0)
    #pragma unroll
    for (int i = 0; i < 32; ++i) {
        if (i < 31) { BFRAG(pf[(i + 1) & 1], i + 1) }
        __builtin_amdgcn_s_setprio(1);
        acc0 = __builtin_amdgcn_mfma_f32_16x16x32_bf16(af[i & 3][0], pf[i & 1], acc0, 0, 0, 0);
        acc1 = __builtin_amdgcn_mfma_f32_16x16x32_bf16(af[i & 3][1], pf[i & 1], acc1, 0, 0, 0);
        __builtin_amdgcn_s_setprio(0);
        if (i < 28) {   // refill the slot just consumed with iteration i+4
            af[i & 3][0] = *(const bf16x8*)&atmTb[r0 + (i + 4) * 32 + kg * 8];
            af[i & 3][1] = *(const bf16x8*)&atmTb[r1 + (i + 4) * 32 + kg * 8];
        }
    }
#undef BFRAG

    // ---- epilogue: scale + LayerNorm (one tiny cross-wave exchange) ----
    psum += __shfl_xor(psum, 16);
    psum += __shfl_xor(psum, 32);
    const int aG = at * 16 + la;
    const float scale = amask[(size_t)b * A + aG] / psum;
    float v0[4], v1[4];
    float s1 = 0.f, s2 = 0.f;
    #pragma unroll
    for (int r = 0; r < 4; ++r) {
        v0[r] = acc0[r] * scale; s1 += v0[r]; s2 += v0[r] * v0[r];
        v1[r] = acc1[r] * scale; s1 += v1[r]; s2 += v1[r] * v1[r];
    }
    s1 += __shfl_xor(s1, 16); s2 += __shfl_xor(s2, 16);
    s1 += __shfl_xor(s1, 32); s2 += __shfl_xor(s2, 32);
    if (kg == 0) { lnP[w][la][0] = s1; lnP[w][la][1] = s2; }
    __syncthreads();
    float S1 = lnP[0][la][0] + lnP[1][la][0] + lnP[2][la][0] + lnP[3][la][0];
    float S2 = lnP[0][la][1] + lnP[1][la][1] + lnP[2][la][1] + lnP[3][la][1];
    const float mu = S1 * (1.f / 128.f);
    const float var = S2 * (1.f / 128.f) - mu * mu;
    const float rs = rsqrtf(var + LN_EPS);
    const size_t obase = ((size_t)b * A + aG) * D;
    {
        int d0 = w * 32 + kg * 4;
        float4 g4 = *(float4*)&gbL[d0];
        float4 b4 = *(float4*)&gbL[128 + d0];
        float4 o;
        o.x = (v0[0] - mu) * rs * g4.x + b4.x;
        o.y = (v0[1] - mu) * rs * g4.y + b4.y;
        o.z = (v0[2] - mu) * rs * g4.z + b4.z;
        o.w = (v0[3] - mu) * rs * g4.w + b4.w;
        *(float4*)&out[obase + d0] = o;
        int d1 = d0 + 16;
        float4 g5 = *(float4*)&gbL[d1];
        float4 b5 = *(float4*)&gbL[128 + d1];
        float4 o2;
        o2.x = (v1[0] - mu) * rs * g5.x + b5.x;
        o2.y = (v1[1] - mu) * rs * g5.y + b5.y;
        o2.z = (v1[2] - mu) * rs * g5.z + b5.z;
        o2.w = (v1[3] - mu) * rs * g5.w + b5.w;
        *(float4*)&out[obase + d1] = o2;
    }
}

// ---------------------------------------------------------------------------
extern "C" void kernel_launch(void* const* d_in, const int* in_sizes, int n_in,
                              void* d_out, int out_size, void* d_ws, size_t ws_size,
                              hipStream_t stream) {
    const float* molf  = (const float*)d_in[0];
    const float* atomf = (const float*)d_in[1];
    const float* amask = (const float*)d_in[2];
    const float* smask = (const float*)d_in[3];
    const float* W_mol = (const float*)d_in[4];
    const float* b_mol = (const float*)d_in[5];
    const float* W_nb  = (const float*)d_in[6];
    const float* b_nb  = (const float*)d_in[7];
    const float* w_am  = (const float*)d_in[8];
    const float* w_aa  = (const float*)d_in[9];
    const float* b_al  = (const float*)d_in[10];
    const float* gamma = (const float*)d_in[11];
    const float* beta  = (const float*)d_in[12];
    float* out = (float*)d_out;

    // ws: atmT bf16 | s_atmM | e_l | f_l | u | c0 | WT bf16 | Mmax keys
    ushort* atmT    = (ushort*)d_ws;
    float* s_atmM   = (float*)(atmT + (size_t)B * D * L);
    float* e_l      = s_atmM + (size_t)B * L;
    float* f_l      = e_l + (size_t)B * L;
    float* u_ws     = f_l + (size_t)B * L;
    float* c0_ws    = u_ws + D;
    ushort* WT      = (ushort*)(c0_ws + 1);
    unsigned* Mmax  = (unsigned*)(WT + D * D);

    prep_kernel<<<128, 128, 0, stream>>>(W_mol, b_mol, w_am, b_al, W_nb,
                                         u_ws, c0_ws, WT, Mmax);
    nb_gemm_kernel<<<(B * L) / 32, 128, 0, stream>>>(atomf, WT, b_nb, w_aa,
                                                     smask, atmT, s_atmM, e_l, f_l, Mmax);
    attn_kernel<<<B * (A / 16), 256, 0, stream>>>(molf, amask, atmT, s_atmM, e_l,
                                                  f_l, u_ws, c0_ws, Mmax,
                                                  gamma, beta, out);
}

// Round 6
// 92.053 us; speedup vs baseline: 3.2307x; 3.2307x over previous
//
#include <hip/hip_runtime.h>
#include <hip/hip_bf16.h>
#include <math.h>

#define NEG_SLOPE 0.2f
#define LN_EPS 1e-5f

constexpr int B = 64, A = 256, L = 1024, D = 128;

typedef float f32x4 __attribute__((ext_vector_type(4)));
typedef short bf16x8 __attribute__((ext_vector_type(8)));

__device__ __forceinline__ ushort f2bf(float x) {
    __hip_bfloat16 h = __float2bfloat16(x);
    return *reinterpret_cast<ushort*>(&h);
}
// monotone float<->uint keys for atomicMax on floats
__device__ __forceinline__ unsigned fkey(float f) {
    int i = __float_as_int(f);
    return (i >= 0) ? ((unsigned)i | 0x80000000u) : ~(unsigned)i;
}
__device__ __forceinline__ float fdecode(unsigned u) {
    int i = (u & 0x80000000u) ? (int)(u & 0x7fffffffu) : ~(int)u;
    return __int_as_float(i);
}

// ---------------------------------------------------------------------------
// prep: u = W_mol @ w_align_mol ; c0 = b_mol.w_align_mol + b_align ;
//       WT[d][e] = bf16(W_nb[e][d]) ; zero-init Mmax keys
// ---------------------------------------------------------------------------
__global__ void prep_kernel(const float* __restrict__ Wmol, const float* __restrict__ bmol,
                            const float* __restrict__ wam, const float* __restrict__ bal,
                            const float* __restrict__ Wnb,
                            float* __restrict__ u, float* __restrict__ c0,
                            ushort* __restrict__ WT, unsigned* __restrict__ Mmax) {
    __shared__ float red[2], red2[2];
    const int d = blockIdx.x, e = threadIdx.x;   // 128 blocks x 128 threads
    const int lane = e & 63, wv = e >> 6;
    if (d == 1 && e < 64) Mmax[e] = 0u;          // key 0 == most negative float
    float p = Wmol[d * D + e] * wam[e];
    #pragma unroll
    for (int o = 1; o < 64; o <<= 1) p += __shfl_xor(p, o);
    WT[d * D + e] = f2bf(Wnb[e * D + d]);
    float q = 0.f;
    if (d == 0) q = bmol[e] * wam[e];
    #pragma unroll
    for (int o = 1; o < 64; o <<= 1) q += __shfl_xor(q, o);
    if (lane == 0) { red[wv] = p; red2[wv] = q; }
    __syncthreads();
    if (e == 0) {
        u[d] = red[0] + red[1];
        if (d == 0) c0[0] = red2[0] + red2[1] + bal[0];
    }
}

// ---------------------------------------------------------------------------
// nb_gemm: 2048 blocks x 128 thr, 32 l-rows per block, MFMA, fp32 epilogue.
// Per-batch masked-max of s_atm via atomicMax(key).
// ---------------------------------------------------------------------------
__global__ __launch_bounds__(128, 4) void nb_gemm_kernel(
    const float* __restrict__ atom, const ushort* __restrict__ WT,
    const float* __restrict__ bias, const float* __restrict__ wa,
    const float* __restrict__ smask,
    ushort* __restrict__ atmT, float* __restrict__ s_atmM,
    float* __restrict__ e_l, float* __restrict__ f_l,
    unsigned* __restrict__ Mmax) {
    __shared__ ushort tb[128][36];   // [d][l-local], padded
    const int tid = threadIdx.x;
    const int wv = tid >> 6, lane = tid & 63, la = lane & 15, kg = lane >> 4;
    const int R0 = blockIdx.x * 32;
    const int b = R0 >> 10, l0 = R0 & 1023;
    const int row = R0 + wv * 16 + la;

    const float* arow = atom + (size_t)row * D + kg * 8;
    bf16x8 af[4];
    #pragma unroll
    for (int ks = 0; ks < 4; ++ks) {
        float4 x0 = *(const float4*)&arow[ks * 32];
        float4 x1 = *(const float4*)&arow[ks * 32 + 4];
        bf16x8 t;
        t[0] = (short)f2bf(x0.x); t[1] = (short)f2bf(x0.y);
        t[2] = (short)f2bf(x0.z); t[3] = (short)f2bf(x0.w);
        t[4] = (short)f2bf(x1.x); t[5] = (short)f2bf(x1.y);
        t[6] = (short)f2bf(x1.z); t[7] = (short)f2bf(x1.w);
        af[ks] = t;
    }
    float wav[8], bv[8];
    #pragma unroll
    for (int dt = 0; dt < 8; ++dt) { wav[dt] = wa[dt * 16 + la]; bv[dt] = bias[dt * 16 + la]; }

    f32x4 acc[8];
    #pragma unroll
    for (int dt = 0; dt < 8; ++dt) acc[dt] = (f32x4){bv[dt], bv[dt], bv[dt], bv[dt]};
    #pragma unroll
    for (int ks = 0; ks < 4; ++ks) {
        #pragma unroll
        for (int dt = 0; dt < 8; ++dt) {
            bf16x8 bf = *(const bf16x8*)&WT[(size_t)(dt * 16 + la) * D + ks * 32 + kg * 8];
            acc[dt] = __builtin_amdgcn_mfma_f32_16x16x32_bf16(af[ks], bf, acc[dt], 0, 0, 0);
        }
    }

    float sr[4];
    #pragma unroll
    for (int r = 0; r < 4; ++r) {
        float t = 0.f;
        #pragma unroll
        for (int dt = 0; dt < 8; ++dt) t += acc[dt][r] * wav[dt];
        t += __shfl_xor(t, 1); t += __shfl_xor(t, 2);
        t += __shfl_xor(t, 4); t += __shfl_xor(t, 8);
        sr[r] = t;
    }
    float mloc = -3.0e38f;
    if (la == 0) {
        #pragma unroll
        for (int r = 0; r < 4; ++r) {
            int l = l0 + wv * 16 + kg * 4 + r;
            float sm = smask[(size_t)b * L + l];
            bool val = sm > -0.5f;
            float sv = sr[r];
            float svm = val ? sv : -1e30f;
            s_atmM[(size_t)b * L + l] = svm;
            e_l[(size_t)b * L + l]    = val ? __expf(sv) : 0.f;
            f_l[(size_t)b * L + l]    = val ? __expf(NEG_SLOPE * sv) : 0.f;
            mloc = fmaxf(mloc, svm);
        }
    }
    #pragma unroll
    for (int o = 1; o < 64; o <<= 1) mloc = fmaxf(mloc, __shfl_xor(mloc, o));
    if (lane == 0) atomicMax(&Mmax[b], fkey(mloc));

    #pragma unroll
    for (int dt = 0; dt < 8; ++dt) {
        union { ushort us[4]; uint2 v; } pk;
        #pragma unroll
        for (int r = 0; r < 4; ++r) pk.us[r] = f2bf(acc[dt][r]);
        *(uint2*)&tb[dt * 16 + la][wv * 16 + kg * 4] = pk.v;
    }
    __syncthreads();
    {
        const int c = tid & 3, dd = tid >> 2;
        #pragma unroll
        for (int j = 0; j < 4; ++j) {
            int d = dd + j * 32;
            *(int4*)&atmT[((size_t)(b * 128 + d) << 10) + l0 + c * 8] =
                *(const int4*)&tb[d][c * 8];
        }
    }
}

// ---------------------------------------------------------------------------
// attn v7: block = (b, 16 a-rows), 4 waves. Wave w owns d-slice [32w,32w+32)
// over FULL L. Phase A: waves cooperatively fill bf16 P[16][1024] in LDS
// (chunk-XOR swizzle), computing psum on the fly (tables read from global,
// 16-lane broadcast, L2-hot). Main loop: 1 LDS b128 + 2 global b128 + 2 MFMA
// per iteration, named-register 4-deep pipeline, ZERO barriers.
// ---------------------------------------------------------------------------
__global__ __launch_bounds__(256, 4) void attn_kernel(
    const float* __restrict__ molf, const float* __restrict__ amask,
    const ushort* __restrict__ atmT,
    const float* __restrict__ s_atmM_g, const float* __restrict__ e_lG,
    const float* __restrict__ f_lG,
    const float* __restrict__ u, const float* __restrict__ c0p,
    const unsigned* __restrict__ Mmax,
    const float* __restrict__ gamma, const float* __restrict__ beta,
    float* __restrict__ out) {
    __shared__ ushort Pl[16 * 1024];               // 32 KB P tile (swizzled)
    __shared__ float thL[16], eaL[16], faL[16];
    __shared__ float gbL[256];
    __shared__ float psumsL[4][16];
    __shared__ float lnP[4][16][2];

    const int bid = blockIdx.x;
    const int lid = (bid & 7) * 128 + (bid >> 3);  // XCD-bijective (1024 % 8 == 0)
    const int b  = lid >> 4;
    const int at = lid & 15;
    const int tid = threadIdx.x;
    const int w = tid >> 6, lane = tid & 63;
    const int la = lane & 15, kg = lane >> 4;

    // ---- prologue: issue first 4 iterations' afrag loads (hide under phases)
    const ushort* atmTb = atmT + (size_t)b * D * L;
    const ushort* pr0 = &atmTb[(size_t)(w * 32 + la) * L + kg * 8];
    const ushort* pr1 = &atmTb[(size_t)(w * 32 + 16 + la) * L + kg * 8];
    bf16x8 a00 = *(const bf16x8*)&pr0[0];
    bf16x8 a01 = *(const bf16x8*)&pr1[0];
    bf16x8 a10 = *(const bf16x8*)&pr0[32];
    bf16x8 a11 = *(const bf16x8*)&pr1[32];
    bf16x8 a20 = *(const bf16x8*)&pr0[64];
    bf16x8 a21 = *(const bf16x8*)&pr1[64];
    bf16x8 a30 = *(const bf16x8*)&pr0[96];
    bf16x8 a31 = *(const bf16x8*)&pr1[96];

    // ---- gamma/beta staging
    if (tid < 32)      ((float4*)gbL)[tid] = ((const float4*)gamma)[tid];
    else if (tid < 64) ((float4*)gbL)[tid] = ((const float4*)beta)[tid - 32];

    // ---- phase 2: s_mol + per-row softmax constants
    {
        float M = fdecode(Mmax[b]);
        int r = tid >> 4, q = tid & 15;
        const float* x = molf + ((size_t)b * A + at * 16 + r) * D + q * 8;
        float4 xa = *(const float4*)x;
        float4 xb = *(const float4*)(x + 4);
        float4 ua = *(const float4*)&u[q * 8];
        float4 ub = *(const float4*)&u[q * 8 + 4];
        float p = xa.x * ua.x + xa.y * ua.y + xa.z * ua.z + xa.w * ua.w
                + xb.x * ub.x + xb.y * ub.y + xb.z * ub.z + xb.w * ub.w;
        p += __shfl_xor(p, 1); p += __shfl_xor(p, 2);
        p += __shfl_xor(p, 4); p += __shfl_xor(p, 8);
        if (q == 0) {
            float sm = p + c0p[0];
            float z = sm + M;
            float m = (z > 0.f) ? z : NEG_SLOPE * z;   // exact row max
            thL[r] = -sm;
            eaL[r] = __expf(sm - m);
            faL[r] = __expf(NEG_SLOPE * sm - m);
        }
    }
    __syncthreads();

    // ---- phase A: P-fill. Wave w covers l in [w*256, (w+1)*256).
    float psum = 0.f;
    {
        const float* sG = s_atmM_g + (size_t)b * L;
        const float* eG = e_lG + (size_t)b * L;
        const float* fG = f_lG + (size_t)b * L;
        const float th = thL[la], ea = eaL[la], fa = faL[la];
        char* Prow = (char*)Pl + la * 2048;
        const int xo = la & 7;
        #pragma unroll 2
        for (int p5 = 0; p5 < 8; ++p5) {
            const int l0 = w * 256 + p5 * 32 + kg * 8;
            float4 s0 = *(const float4*)&sG[l0];
            float4 s1 = *(const float4*)&sG[l0 + 4];
            float4 e0 = *(const float4*)&eG[l0];
            float4 e1 = *(const float4*)&eG[l0 + 4];
            float4 f0 = *(const float4*)&fG[l0];
            float4 f1 = *(const float4*)&fG[l0 + 4];
            float p0 = (s0.x > th) ? ea * e0.x : fa * f0.x;
            float p1 = (s0.y > th) ? ea * e0.y : fa * f0.y;
            float p2 = (s0.z > th) ? ea * e0.z : fa * f0.z;
            float p3 = (s0.w > th) ? ea * e0.w : fa * f0.w;
            float p4 = (s1.x > th) ? ea * e1.x : fa * f1.x;
            float p5v = (s1.y > th) ? ea * e1.y : fa * f1.y;
            float p6 = (s1.z > th) ? ea * e1.z : fa * f1.z;
            float p7 = (s1.w > th) ? ea * e1.w : fa * f1.w;
            psum += (p0 + p1) + (p2 + p3) + ((p4 + p5v) + (p6 + p7));
            union { ushort us[8]; int4 v; } pk;
            pk.us[0] = f2bf(p0); pk.us[1] = f2bf(p1);
            pk.us[2] = f2bf(p2); pk.us[3] = f2bf(p3);
            pk.us[4] = f2bf(p4); pk.us[5] = f2bf(p5v);
            pk.us[6] = f2bf(p6); pk.us[7] = f2bf(p7);
            const int ch = (l0 >> 3) ^ xo;
            *(int4*)(Prow + ch * 16) = pk.v;
        }
    }
    psum += __shfl_xor(psum, 16);
    psum += __shfl_xor(psum, 32);
    if (lane < 16) psumsL[w][la] = psum;
    __syncthreads();

    // ---- main loop: zero barriers, named-register 4-deep pipeline
    const char* Pbase = (const char*)Pl + la * 2048;
    const int xo = la & 7;
#define LDP(I_) (*(const bf16x8*)(Pbase + ((((I_) * 4 + kg) ^ xo) * 16)))
    f32x4 acc0 = {}, acc1 = {};
    #pragma unroll
    for (int i = 0; i < 32; i += 4) {
        {
            bf16x8 p_ = LDP(i);
            acc0 = __builtin_amdgcn_mfma_f32_16x16x32_bf16(a00, p_, acc0, 0, 0, 0);
            acc1 = __builtin_amdgcn_mfma_f32_16x16x32_bf16(a01, p_, acc1, 0, 0, 0);
            if (i < 28) { a00 = *(const bf16x8*)&pr0[(i + 4) * 32];
                          a01 = *(const bf16x8*)&pr1[(i + 4) * 32]; }
        }
        {
            bf16x8 p_ = LDP(i + 1);
            acc0 = __builtin_amdgcn_mfma_f32_16x16x32_bf16(a10, p_, acc0, 0, 0, 0);
            acc1 = __builtin_amdgcn_mfma_f32_16x16x32_bf16(a11, p_, acc1, 0, 0, 0);
            if (i < 28) { a10 = *(const bf16x8*)&pr0[(i + 5) * 32];
                          a11 = *(const bf16x8*)&pr1[(i + 5) * 32]; }
        }
        {
            bf16x8 p_ = LDP(i + 2);
            acc0 = __builtin_amdgcn_mfma_f32_16x16x32_bf16(a20, p_, acc0, 0, 0, 0);
            acc1 = __builtin_amdgcn_mfma_f32_16x16x32_bf16(a21, p_, acc1, 0, 0, 0);
            if (i < 28) { a20 = *(const bf16x8*)&pr0[(i + 6) * 32];
                          a21 = *(const bf16x8*)&pr1[(i + 6) * 32]; }
        }
        {
            bf16x8 p_ = LDP(i + 3);
            acc0 = __builtin_amdgcn_mfma_f32_16x16x32_bf16(a30, p_, acc0, 0, 0, 0);
            acc1 = __builtin_amdgcn_mfma_f32_16x16x32_bf16(a31, p_, acc1, 0, 0, 0);
            if (i < 28) { a30 = *(const bf16x8*)&pr0[(i + 7) * 32];
                          a31 = *(const bf16x8*)&pr1[(i + 7) * 32]; }
        }
    }
#undef LDP

    // ---- epilogue: scale + LayerNorm
    const float psT = psumsL[0][la] + psumsL[1][la] + psumsL[2][la] + psumsL[3][la];
    const int aG = at * 16 + la;
    const float scale = amask[(size_t)b * A + aG] / psT;
    float v0[4], v1[4];
    float s1 = 0.f, s2 = 0.f;
    #pragma unroll
    for (int r = 0; r < 4; ++r) {
        v0[r] = acc0[r] * scale; s1 += v0[r]; s2 += v0[r] * v0[r];
        v1[r] = acc1[r] * scale; s1 += v1[r]; s2 += v1[r] * v1[r];
    }
    s1 += __shfl_xor(s1, 16); s2 += __shfl_xor(s2, 16);
    s1 += __shfl_xor(s1, 32); s2 += __shfl_xor(s2, 32);
    if (kg == 0) { lnP[w][la][0] = s1; lnP[w][la][1] = s2; }
    __syncthreads();
    float S1 = lnP[0][la][0] + lnP[1][la][0] + lnP[2][la][0] + lnP[3][la][0];
    float S2 = lnP[0][la][1] + lnP[1][la][1] + lnP[2][la][1] + lnP[3][la][1];
    const float mu = S1 * (1.f / 128.f);
    const float var = S2 * (1.f / 128.f) - mu * mu;
    const float rs = rsqrtf(var + LN_EPS);
    const size_t obase = ((size_t)b * A + aG) * D;
    {
        int d0 = w * 32 + kg * 4;
        float4 g4 = *(float4*)&gbL[d0];
        float4 b4 = *(float4*)&gbL[128 + d0];
        float4 o;
        o.x = (v0[0] - mu) * rs * g4.x + b4.x;
        o.y = (v0[1] - mu) * rs * g4.y + b4.y;
        o.z = (v0[2] - mu) * rs * g4.z + b4.z;
        o.w = (v0[3] - mu) * rs * g4.w + b4.w;
        *(float4*)&out[obase + d0] = o;
        int d1 = d0 + 16;
        float4 g5 = *(float4*)&gbL[d1];
        float4 b5 = *(float4*)&gbL[128 + d1];
        float4 o2;
        o2.x = (v1[0] - mu) * rs * g5.x + b5.x;
        o2.y = (v1[1] - mu) * rs * g5.y + b5.y;
        o2.z = (v1[2] - mu) * rs * g5.z + b5.z;
        o2.w = (v1[3] - mu) * rs * g5.w + b5.w;
        *(float4*)&out[obase + d1] = o2;
    }
}

// ---------------------------------------------------------------------------
extern "C" void kernel_launch(void* const* d_in, const int* in_sizes, int n_in,
                              void* d_out, int out_size, void* d_ws, size_t ws_size,
                              hipStream_t stream) {
    const float* molf  = (const float*)d_in[0];
    const float* atomf = (const float*)d_in[1];
    const float* amask = (const float*)d_in[2];
    const float* smask = (const float*)d_in[3];
    const float* W_mol = (const float*)d_in[4];
    const float* b_mol = (const float*)d_in[5];
    const float* W_nb  = (const float*)d_in[6];
    const float* b_nb  = (const float*)d_in[7];
    const float* w_am  = (const float*)d_in[8];
    const float* w_aa  = (const float*)d_in[9];
    const float* b_al  = (const float*)d_in[10];
    const float* gamma = (const float*)d_in[11];
    const float* beta  = (const float*)d_in[12];
    float* out = (float*)d_out;

    // ws: atmT bf16 | s_atmM | e_l | f_l | u | c0 | WT bf16 | Mmax keys
    ushort* atmT    = (ushort*)d_ws;
    float* s_atmM   = (float*)(atmT + (size_t)B * D * L);
    float* e_l      = s_atmM + (size_t)B * L;
    float* f_l      = e_l + (size_t)B * L;
    float* u_ws     = f_l + (size_t)B * L;
    float* c0_ws    = u_ws + D;
    ushort* WT      = (ushort*)(c0_ws + 1);
    unsigned* Mmax  = (unsigned*)(WT + D * D);

    prep_kernel<<<128, 128, 0, stream>>>(W_mol, b_mol, w_am, b_al, W_nb,
                                         u_ws, c0_ws, WT, Mmax);
    nb_gemm_kernel<<<(B * L) / 32, 128, 0, stream>>>(atomf, WT, b_nb, w_aa,
                                                     smask, atmT, s_atmM, e_l, f_l, Mmax);
    attn_kernel<<<B * (A / 16), 256, 0, stream>>>(molf, amask, atmT, s_atmM, e_l,
                                                  f_l, u_ws, c0_ws, Mmax,
                                                  gamma, beta, out);
}

// Round 7
// 49.041 us; speedup vs baseline: 6.0642x; 1.8771x over previous
//
#include <hip/hip_runtime.h>
#include <hip/hip_bf16.h>
#include <math.h>

#define NEG_SLOPE 0.2f
#define LN_EPS 1e-5f

constexpr int B = 64, A = 256, L = 1024, D = 128;

typedef float f32x4 __attribute__((ext_vector_type(4)));
typedef short bf16x8 __attribute__((ext_vector_type(8)));

__device__ __forceinline__ ushort f2bf(float x) {
    __hip_bfloat16 h = __float2bfloat16(x);
    return *reinterpret_cast<ushort*>(&h);
}
__device__ __forceinline__ float bf2f(ushort x) {
    unsigned u = ((unsigned)x) << 16;
    return __uint_as_float(u);
}

// ---------------------------------------------------------------------------
// prep: u = W_mol@w_am, v = W_nb@w_aa, c0 = b_mol.w_am + b_al, c1 = b_nb.w_aa,
//       WB[e][d] = bf16(W_nb[d][e])   (A-operand for the ctx GEMM)
// ---------------------------------------------------------------------------
__global__ void prep_kernel(const float* __restrict__ Wmol, const float* __restrict__ bmol,
                            const float* __restrict__ wam, const float* __restrict__ bal,
                            const float* __restrict__ Wnb, const float* __restrict__ bnb,
                            const float* __restrict__ waa,
                            float* __restrict__ u, float* __restrict__ v,
                            float* __restrict__ c0, float* __restrict__ c1,
                            ushort* __restrict__ WB) {
    __shared__ float redU[2], redV[2], redC0[2], redC1[2];
    const int i = blockIdx.x, e = threadIdx.x;   // 128 blocks x 128 threads
    const int lane = e & 63, wv = e >> 6;
    float wnb_ie = Wnb[i * D + e];
    WB[e * D + i] = f2bf(wnb_ie);                // WB[e][d=i] = Wnb[i][e]
    float pu = Wmol[i * D + e] * wam[e];
    float pv = wnb_ie * waa[e];
    float q0 = (i == 0) ? bmol[e] * wam[e] : 0.f;
    float q1 = (i == 0) ? bnb[e] * waa[e] : 0.f;
    #pragma unroll
    for (int o = 1; o < 64; o <<= 1) {
        pu += __shfl_xor(pu, o); pv += __shfl_xor(pv, o);
        q0 += __shfl_xor(q0, o); q1 += __shfl_xor(q1, o);
    }
    if (lane == 0) { redU[wv] = pu; redV[wv] = pv; redC0[wv] = q0; redC1[wv] = q1; }
    __syncthreads();
    if (e == 0) {
        u[i] = redU[0] + redU[1];
        v[i] = redV[0] + redV[1];
        if (i == 0) { c0[0] = redC0[0] + redC0[1] + bal[0];
                      c1[0] = redC1[0] + redC1[1]; }
    }
}

// ---------------------------------------------------------------------------
// trans: streaming atom fp32 -> atomT bf16 [b][d][l] (LDS transpose) and
//        s_atm[b][l] = atom[b,l].v + c1 (masked). No MFMA, no atomics.
// 1024 blocks x 256 thr, 64 l-rows per block.
// ---------------------------------------------------------------------------
__global__ __launch_bounds__(256) void trans_kernel(
    const float* __restrict__ atom, const float* __restrict__ v,
    const float* __restrict__ c1p, const float* __restrict__ smask,
    ushort* __restrict__ atomT, float* __restrict__ sM) {
    __shared__ ushort Ls[64][132];   // [l-local][d] bf16, padded
    const int tid = threadIdx.x;
    const int q = tid & 31, rg = tid >> 5;       // q: d-quad, rg: 0..7
    const int bidx = blockIdx.x;
    const int b = bidx >> 4, l0 = (bidx & 15) * 64;
    const float4 vq = *(const float4*)&v[q * 4];
    const float c1 = c1p[0];

    #pragma unroll
    for (int k = 0; k < 8; ++k) {
        const int l = rg * 8 + k;
        float4 x = *(const float4*)&atom[((size_t)b * L + l0 + l) * D + q * 4];
        float dot = x.x * vq.x + x.y * vq.y + x.z * vq.z + x.w * vq.w;
        dot += __shfl_xor(dot, 1);  dot += __shfl_xor(dot, 2);
        dot += __shfl_xor(dot, 4);  dot += __shfl_xor(dot, 8);
        dot += __shfl_xor(dot, 16);
        union { ushort us[4]; uint2 u2; } pk;
        pk.us[0] = f2bf(x.x); pk.us[1] = f2bf(x.y);
        pk.us[2] = f2bf(x.z); pk.us[3] = f2bf(x.w);
        *(uint2*)&Ls[l][q * 4] = pk.u2;
        if (q == 0) {
            float msk = smask[(size_t)b * L + l0 + l];
            sM[(size_t)b * L + l0 + l] = (msk > -0.5f) ? (dot + c1) : -1e30f;
        }
    }
    __syncthreads();
    {   // transposed write-out: thread = (d = tid>>1, h = tid&1)
        const int d = tid >> 1, h = tid & 1;
        #pragma unroll
        for (int j = 0; j < 4; ++j) {
            alignas(16) ushort tmp[8];
            #pragma unroll
            for (int m = 0; m < 8; ++m) tmp[m] = Ls[h * 32 + j * 8 + m][d];
            *(int4*)&atomT[((size_t)(b * 128 + d) << 10) + l0 + h * 32 + j * 8] =
                *(int4*)tmp;
        }
    }
}

// ---------------------------------------------------------------------------
// attn v8: block = (b, 32 a-rows), 4 waves; wave w owns d/e-slice [32w,32w+32).
// Phases: A0 tables(bf16)+batch-max | B s_mol consts | C P-fill (2 planes)
// | D PV main loop (atomT afrag 4-deep, 2 ds + 4 MFMA/iter, no barriers)
// | E T->TT bounce (XOR-swizzled, aliases P plane0) | F ctx = T.W MFMA + LN.
// ---------------------------------------------------------------------------
__global__ __launch_bounds__(256, 2) void attn_kernel(
    const float* __restrict__ molf, const float* __restrict__ amask,
    const ushort* __restrict__ atomT, const float* __restrict__ sM_g,
    const float* __restrict__ u, const float* __restrict__ c0p,
    const ushort* __restrict__ WB, const float* __restrict__ bnb,
    const float* __restrict__ gamma, const float* __restrict__ beta,
    float* __restrict__ out) {
    __shared__ ushort Pl[2][16384];              // 64 KB, planes A/B (TT aliases A)
    __shared__ ushort sLb[1024], eLb[1024], fLb[1024];   // 6 KB bf16 tables
    __shared__ float thL[32], eaL[32], faL[32];
    __shared__ float wmaxL[4];
    __shared__ float psumsL[4][32];
    __shared__ float lnP[4][2][16][2];
    __shared__ float gbL[256];

    const int bid = blockIdx.x;
    const int lid = (bid & 7) * 64 + (bid >> 3);   // XCD-bijective (512 % 8 == 0)
    const int b  = lid >> 3;
    const int at = lid & 7;                        // 8 tiles of 32 a-rows
    const int tid = threadIdx.x;
    const int w = tid >> 6, lane = tid & 63;
    const int la = lane & 15, kg = lane >> 4;
    const int xo = la & 7;

    // ---- prologue: first 4 iterations' afrag loads (longest latency first)
    const ushort* atomTb = atomT + (size_t)b * D * L;
    const ushort* pr0 = &atomTb[(size_t)(w * 32 + la) * L + kg * 8];
    const ushort* pr1 = &atomTb[(size_t)(w * 32 + 16 + la) * L + kg * 8];
    bf16x8 a00 = *(const bf16x8*)&pr0[0],  a01 = *(const bf16x8*)&pr1[0];
    bf16x8 a10 = *(const bf16x8*)&pr0[32], a11 = *(const bf16x8*)&pr1[32];
    bf16x8 a20 = *(const bf16x8*)&pr0[64], a21 = *(const bf16x8*)&pr1[64];
    bf16x8 a30 = *(const bf16x8*)&pr0[96], a31 = *(const bf16x8*)&pr1[96];

    if (tid < 32)      ((float4*)gbL)[tid] = ((const float4*)gamma)[tid];
    else if (tid < 64) ((float4*)gbL)[tid] = ((const float4*)beta)[tid - 32];

    // ---- phase A0: softmax tables (bf16) + batch max
    {
        const int i4 = tid * 4;
        float4 sa = *(const float4*)&sM_g[(size_t)b * L + i4];
        union { ushort us[4]; uint2 u2; } ps, pe, pf;
        ps.us[0] = f2bf(sa.x); ps.us[1] = f2bf(sa.y);
        ps.us[2] = f2bf(sa.z); ps.us[3] = f2bf(sa.w);
        pe.us[0] = f2bf(__expf(sa.x)); pe.us[1] = f2bf(__expf(sa.y));
        pe.us[2] = f2bf(__expf(sa.z)); pe.us[3] = f2bf(__expf(sa.w));
        pf.us[0] = f2bf(__expf(NEG_SLOPE * sa.x)); pf.us[1] = f2bf(__expf(NEG_SLOPE * sa.y));
        pf.us[2] = f2bf(__expf(NEG_SLOPE * sa.z)); pf.us[3] = f2bf(__expf(NEG_SLOPE * sa.w));
        *(uint2*)&sLb[i4] = ps.u2; *(uint2*)&eLb[i4] = pe.u2; *(uint2*)&fLb[i4] = pf.u2;
        float mx = fmaxf(fmaxf(sa.x, sa.y), fmaxf(sa.z, sa.w));
        #pragma unroll
        for (int o = 1; o < 64; o <<= 1) mx = fmaxf(mx, __shfl_xor(mx, o));
        if (lane == 0) wmaxL[w] = mx;
    }
    __syncthreads();

    // ---- phase B: s_mol + per-row constants (32 rows x 8 threads)
    {
        const float M = fmaxf(fmaxf(wmaxL[0], wmaxL[1]), fmaxf(wmaxL[2], wmaxL[3]));
        const int r = tid >> 3, q = tid & 7;
        const float* x = molf + ((size_t)b * A + at * 32 + r) * D + q * 16;
        float p = 0.f;
        #pragma unroll
        for (int k = 0; k < 4; ++k) {
            float4 xv = *(const float4*)&x[k * 4];
            float4 uv = *(const float4*)&u[q * 16 + k * 4];
            p += xv.x * uv.x + xv.y * uv.y + xv.z * uv.z + xv.w * uv.w;
        }
        p += __shfl_xor(p, 1); p += __shfl_xor(p, 2); p += __shfl_xor(p, 4);
        if (q == 0) {
            float sm = p + c0p[0];
            float z = sm + M;
            float m = (z > 0.f) ? z : NEG_SLOPE * z;   // exact row max
            thL[r] = -sm;
            eaL[r] = __expf(sm - m);
            faL[r] = __expf(NEG_SLOPE * sm - m);
        }
    }
    __syncthreads();

    // ---- phase C: P-fill, wave w covers l in [w*256,(w+1)*256), both planes
    float psum0 = 0.f, psum1 = 0.f;
    {
        const float thA = thL[la],      eaA = eaL[la],      faA = faL[la];
        const float thB = thL[la + 16], eaB = eaL[la + 16], faB = faL[la + 16];
        char* PrA = (char*)&Pl[0][0] + la * 2048;
        char* PrB = (char*)&Pl[1][0] + la * 2048;
        #pragma unroll 2
        for (int p5 = 0; p5 < 8; ++p5) {
            const int l0 = w * 256 + p5 * 32 + kg * 8;
            bf16x8 sb = *(const bf16x8*)&sLb[l0];
            bf16x8 eb = *(const bf16x8*)&eLb[l0];
            bf16x8 fb = *(const bf16x8*)&fLb[l0];
            union { ushort us[8]; int4 v; } pkA, pkB;
            #pragma unroll
            for (int j = 0; j < 8; ++j) {
                float s = bf2f((ushort)sb[j]);
                float e = bf2f((ushort)eb[j]);
                float f = bf2f((ushort)fb[j]);
                float pA = (s > thA) ? eaA * e : faA * f;
                float pB = (s > thB) ? eaB * e : faB * f;
                psum0 += pA; psum1 += pB;
                pkA.us[j] = f2bf(pA); pkB.us[j] = f2bf(pB);
            }
            const int slot = ((w * 32 + p5 * 4 + kg) ^ xo) * 16;
            *(int4*)(PrA + slot) = pkA.v;
            *(int4*)(PrB + slot) = pkB.v;
        }
    }
    psum0 += __shfl_xor(psum0, 16); psum0 += __shfl_xor(psum0, 32);
    psum1 += __shfl_xor(psum1, 16); psum1 += __shfl_xor(psum1, 32);
    if (lane < 16) { psumsL[w][la] = psum0; psumsL[w][la + 16] = psum1; }
    __syncthreads();

    // ---- phase D: PV main loop (no barriers)
    const char* PbA = (const char*)&Pl[0][0] + la * 2048;
    const char* PbB = (const char*)&Pl[1][0] + la * 2048;
#define LDPA(I_) (*(const bf16x8*)(PbA + ((((I_) * 4 + kg) ^ xo) * 16)))
#define LDPB(I_) (*(const bf16x8*)(PbB + ((((I_) * 4 + kg) ^ xo) * 16)))
    f32x4 acc0a = {}, acc1a = {}, acc0b = {}, acc1b = {};
#define STEP(S0_, S1_, I_)                                                     \
    {                                                                          \
        bf16x8 bA = LDPA(I_); bf16x8 bB = LDPB(I_);                            \
        acc0a = __builtin_amdgcn_mfma_f32_16x16x32_bf16(S0_, bA, acc0a, 0, 0, 0); \
        acc1a = __builtin_amdgcn_mfma_f32_16x16x32_bf16(S1_, bA, acc1a, 0, 0, 0); \
        acc0b = __builtin_amdgcn_mfma_f32_16x16x32_bf16(S0_, bB, acc0b, 0, 0, 0); \
        acc1b = __builtin_amdgcn_mfma_f32_16x16x32_bf16(S1_, bB, acc1b, 0, 0, 0); \
        if ((I_) < 28) { S0_ = *(const bf16x8*)&pr0[((I_) + 4) * 32];          \
                         S1_ = *(const bf16x8*)&pr1[((I_) + 4) * 32]; }        \
    }
    #pragma unroll
    for (int i = 0; i < 32; i += 4) {
        STEP(a00, a01, i)
        STEP(a10, a11, i + 1)
        STEP(a20, a21, i + 2)
        STEP(a30, a31, i + 3)
    }
#undef STEP
#undef LDPA
#undef LDPB

    // ---- prefetch ctx-GEMM operands before the barrier
    bf16x8 wb0[4], wb1[4];
    {
        const ushort* wr0 = WB + (size_t)((2 * w) * 16 + la) * D + kg * 8;
        const ushort* wr1 = WB + (size_t)((2 * w + 1) * 16 + la) * D + kg * 8;
        #pragma unroll
        for (int ks = 0; ks < 4; ++ks) {
            wb0[ks] = *(const bf16x8*)&wr0[ks * 32];
            wb1[ks] = *(const bf16x8*)&wr1[ks * 32];
        }
    }
    float4 bias0 = *(const float4*)&bnb[w * 32 + kg * 4];
    float4 bias1 = *(const float4*)&bnb[w * 32 + 16 + kg * 4];
    const float amA = amask[(size_t)b * A + at * 32 + la];
    const float amB = amask[(size_t)b * A + at * 32 + 16 + la];
    __syncthreads();   // all Pl reads done -> safe to alias TT onto plane A

    // ---- phase E: bounce T (bf16) into TT[32][128] (XOR-swizzled chunks)
    {
        ushort* TT = &Pl[0][0];
        const int ch0 = w * 4 + (kg >> 1);
        const int ch1 = ch0 + 2;
        const int sub = (kg & 1) * 8;
        union { ushort us[4]; uint2 u2; } k0, k1;
        #pragma unroll
        for (int r = 0; r < 4; ++r) { k0.us[r] = f2bf(acc0a[r]); k1.us[r] = f2bf(acc1a[r]); }
        *(uint2*)((char*)TT + la * 256 + ((ch0 ^ xo) * 16) + sub) = k0.u2;
        *(uint2*)((char*)TT + la * 256 + ((ch1 ^ xo) * 16) + sub) = k1.u2;
        #pragma unroll
        for (int r = 0; r < 4; ++r) { k0.us[r] = f2bf(acc0b[r]); k1.us[r] = f2bf(acc1b[r]); }
        *(uint2*)((char*)TT + (la + 16) * 256 + ((ch0 ^ xo) * 16) + sub) = k0.u2;
        *(uint2*)((char*)TT + (la + 16) * 256 + ((ch1 ^ xo) * 16) + sub) = k1.u2;
    }
    __syncthreads();

    // ---- phase F: ctx = T.W (16 MFMA/wave) + LayerNorm
    const ushort* TT = &Pl[0][0];
#define LDT(ROW_, KS_) (*(const bf16x8*)((const char*)TT + (ROW_) * 256 + \
                         ((((KS_) * 4 + kg) ^ xo) * 16)))
    f32x4 cA0 = {}, cA1 = {}, cB0 = {}, cB1 = {};
    #pragma unroll
    for (int ks = 0; ks < 4; ++ks) {
        bf16x8 tA = LDT(la, ks);
        bf16x8 tB = LDT(la + 16, ks);
        cA0 = __builtin_amdgcn_mfma_f32_16x16x32_bf16(wb0[ks], tA, cA0, 0, 0, 0);
        cA1 = __builtin_amdgcn_mfma_f32_16x16x32_bf16(wb1[ks], tA, cA1, 0, 0, 0);
        cB0 = __builtin_amdgcn_mfma_f32_16x16x32_bf16(wb0[ks], tB, cB0, 0, 0, 0);
        cB1 = __builtin_amdgcn_mfma_f32_16x16x32_bf16(wb1[ks], tB, cB1, 0, 0, 0);
    }
#undef LDT

    const float psA = psumsL[0][la] + psumsL[1][la] + psumsL[2][la] + psumsL[3][la];
    const float psB = psumsL[0][la + 16] + psumsL[1][la + 16]
                    + psumsL[2][la + 16] + psumsL[3][la + 16];
    const float scA = amA / psA, scB = amB / psB;
    float xA[8], xB[8];
    float s1A = 0.f, s2A = 0.f, s1B = 0.f, s2B = 0.f;
    const float* bp0 = (const float*)&bias0;
    const float* bp1 = (const float*)&bias1;
    #pragma unroll
    for (int r = 0; r < 4; ++r) {
        xA[r]     = cA0[r] * scA + amA * bp0[r];
        xA[4 + r] = cA1[r] * scA + amA * bp1[r];
        xB[r]     = cB0[r] * scB + amB * bp0[r];
        xB[4 + r] = cB1[r] * scB + amB * bp1[r];
        s1A += xA[r] + xA[4 + r]; s2A += xA[r] * xA[r] + xA[4 + r] * xA[4 + r];
        s1B += xB[r] + xB[4 + r]; s2B += xB[r] * xB[r] + xB[4 + r] * xB[4 + r];
    }
    s1A += __shfl_xor(s1A, 16); s1A += __shfl_xor(s1A, 32);
    s2A += __shfl_xor(s2A, 16); s2A += __shfl_xor(s2A, 32);
    s1B += __shfl_xor(s1B, 16); s1B += __shfl_xor(s1B, 32);
    s2B += __shfl_xor(s2B, 16); s2B += __shfl_xor(s2B, 32);
    if (lane < 16) {
        lnP[w][0][la][0] = s1A; lnP[w][0][la][1] = s2A;
        lnP[w][1][la][0] = s1B; lnP[w][1][la][1] = s2B;
    }
    __syncthreads();
    const float S1A = lnP[0][0][la][0] + lnP[1][0][la][0] + lnP[2][0][la][0] + lnP[3][0][la][0];
    const float S2A = lnP[0][0][la][1] + lnP[1][0][la][1] + lnP[2][0][la][1] + lnP[3][0][la][1];
    const float S1B = lnP[0][1][la][0] + lnP[1][1][la][0] + lnP[2][1][la][0] + lnP[3][1][la][0];
    const float S2B = lnP[0][1][la][1] + lnP[1][1][la][1] + lnP[2][1][la][1] + lnP[3][1][la][1];
    const float muA = S1A * (1.f / 128.f);
    const float rsA = rsqrtf(S2A * (1.f / 128.f) - muA * muA + LN_EPS);
    const float muB = S1B * (1.f / 128.f);
    const float rsB = rsqrtf(S2B * (1.f / 128.f) - muB * muB + LN_EPS);
    const size_t oA = ((size_t)b * A + at * 32 + la) * D;
    const size_t oB = ((size_t)b * A + at * 32 + 16 + la) * D;
    #pragma unroll
    for (int t = 0; t < 2; ++t) {
        const int e0 = w * 32 + t * 16 + kg * 4;
        float4 g4 = *(float4*)&gbL[e0];
        float4 b4 = *(float4*)&gbL[128 + e0];
        float4 ovA, ovB;
        const float* xpA = &xA[t * 4];
        const float* xpB = &xB[t * 4];
        ((float*)&ovA)[0] = (xpA[0] - muA) * rsA * g4.x + b4.x;
        ((float*)&ovA)[1] = (xpA[1] - muA) * rsA * g4.y + b4.y;
        ((float*)&ovA)[2] = (xpA[2] - muA) * rsA * g4.z + b4.z;
        ((float*)&ovA)[3] = (xpA[3] - muA) * rsA * g4.w + b4.w;
        ((float*)&ovB)[0] = (xpB[0] - muB) * rsB * g4.x + b4.x;
        ((float*)&ovB)[1] = (xpB[1] - muB) * rsB * g4.y + b4.y;
        ((float*)&ovB)[2] = (xpB[2] - muB) * rsB * g4.z + b4.z;
        ((float*)&ovB)[3] = (xpB[3] - muB) * rsB * g4.w + b4.w;
        *(float4*)&out[oA + e0] = ovA;
        *(float4*)&out[oB + e0] = ovB;
    }
}

// ---------------------------------------------------------------------------
extern "C" void kernel_launch(void* const* d_in, const int* in_sizes, int n_in,
                              void* d_out, int out_size, void* d_ws, size_t ws_size,
                              hipStream_t stream) {
    const float* molf  = (const float*)d_in[0];
    const float* atomf = (const float*)d_in[1];
    const float* amask = (const float*)d_in[2];
    const float* smask = (const float*)d_in[3];
    const float* W_mol = (const float*)d_in[4];
    const float* b_mol = (const float*)d_in[5];
    const float* W_nb  = (const float*)d_in[6];
    const float* b_nb  = (const float*)d_in[7];
    const float* w_am  = (const float*)d_in[8];
    const float* w_aa  = (const float*)d_in[9];
    const float* b_al  = (const float*)d_in[10];
    const float* gamma = (const float*)d_in[11];
    const float* beta  = (const float*)d_in[12];
    float* out = (float*)d_out;

    // ws: atomT bf16 [B*D*L] | sM [B*L] | u,v [D] | c0,c1 | WB bf16 [D*D]
    ushort* atomT = (ushort*)d_ws;
    float* sM     = (float*)(atomT + (size_t)B * D * L);
    float* u_ws   = sM + (size_t)B * L;
    float* v_ws   = u_ws + D;
    float* c0_ws  = v_ws + D;
    float* c1_ws  = c0_ws + 1;
    ushort* WB    = (ushort*)(c1_ws + 1);

    prep_kernel<<<128, 128, 0, stream>>>(W_mol, b_mol, w_am, b_al, W_nb, b_nb,
                                         w_aa, u_ws, v_ws, c0_ws, c1_ws, WB);
    trans_kernel<<<(B * L) / 64, 256, 0, stream>>>(atomf, v_ws, c1_ws, smask,
                                                   atomT, sM);
    attn_kernel<<<B * (A / 32), 256, 0, stream>>>(molf, amask, atomT, sM, u_ws,
                                                  c0_ws, WB, b_nb, gamma, beta, out);
}

// Round 8
// 48.866 us; speedup vs baseline: 6.0859x; 1.0036x over previous
//
#include <hip/hip_runtime.h>
#include <hip/hip_bf16.h>
#include <math.h>

#define NEG_SLOPE 0.2f
#define LN_EPS 1e-5f

constexpr int B = 64, A = 256, L = 1024, D = 128;

typedef float f32x4 __attribute__((ext_vector_type(4)));
typedef short bf16x8 __attribute__((ext_vector_type(8)));

__device__ __forceinline__ ushort f2bf(float x) {
    __hip_bfloat16 h = __float2bfloat16(x);
    return *reinterpret_cast<ushort*>(&h);
}
__device__ __forceinline__ float bf2f(ushort x) {
    unsigned u = ((unsigned)x) << 16;
    return __uint_as_float(u);
}

// ---------------------------------------------------------------------------
// prep: u = W_mol@w_am, v = W_nb@w_aa, c0 = b_mol.w_am + b_al, c1 = b_nb.w_aa,
//       WB[e][d] = bf16(W_nb[d][e])   (A-operand for the ctx GEMM)
// ---------------------------------------------------------------------------
__global__ void prep_kernel(const float* __restrict__ Wmol, const float* __restrict__ bmol,
                            const float* __restrict__ wam, const float* __restrict__ bal,
                            const float* __restrict__ Wnb, const float* __restrict__ bnb,
                            const float* __restrict__ waa,
                            float* __restrict__ u, float* __restrict__ v,
                            float* __restrict__ c0, float* __restrict__ c1,
                            ushort* __restrict__ WB) {
    __shared__ float redU[2], redV[2], redC0[2], redC1[2];
    const int i = blockIdx.x, e = threadIdx.x;   // 128 blocks x 128 threads
    const int lane = e & 63, wv = e >> 6;
    float wnb_ie = Wnb[i * D + e];
    WB[e * D + i] = f2bf(wnb_ie);                // WB[e][d=i] = Wnb[i][e]
    float pu = Wmol[i * D + e] * wam[e];
    float pv = wnb_ie * waa[e];
    float q0 = (i == 0) ? bmol[e] * wam[e] : 0.f;
    float q1 = (i == 0) ? bnb[e] * waa[e] : 0.f;
    #pragma unroll
    for (int o = 1; o < 64; o <<= 1) {
        pu += __shfl_xor(pu, o); pv += __shfl_xor(pv, o);
        q0 += __shfl_xor(q0, o); q1 += __shfl_xor(q1, o);
    }
    if (lane == 0) { redU[wv] = pu; redV[wv] = pv; redC0[wv] = q0; redC1[wv] = q1; }
    __syncthreads();
    if (e == 0) {
        u[i] = redU[0] + redU[1];
        v[i] = redV[0] + redV[1];
        if (i == 0) { c0[0] = redC0[0] + redC0[1] + bal[0];
                      c1[0] = redC1[0] + redC1[1]; }
    }
}

// ---------------------------------------------------------------------------
// trans: streaming atom fp32 -> atomT bf16 [b][d][l] (LDS transpose) and
//        s_atm[b][l] = atom[b,l].v + c1 (masked).
// XCD co-location: batch b handled ONLY by blocks with bid%8 == b%8, so the
// slab lands in the same XCD L2 that attn (same mapping) will read.
// ---------------------------------------------------------------------------
__global__ __launch_bounds__(256) void trans_kernel(
    const float* __restrict__ atom, const float* __restrict__ v,
    const float* __restrict__ c1p, const float* __restrict__ smask,
    ushort* __restrict__ atomT, float* __restrict__ sM) {
    __shared__ ushort Ls[64][132];   // [l-local][d] bf16, padded
    const int tid = threadIdx.x;
    const int q = tid & 31, rg = tid >> 5;       // q: d-quad, rg: 0..7
    const int bidx = blockIdx.x;
    const int x = bidx & 7, j = bidx >> 3;       // x = XCD slot
    const int b = x + 8 * (j & 7);               // b % 8 == bid % 8
    const int l0 = (j >> 3) * 64;
    const float4 vq = *(const float4*)&v[q * 4];
    const float c1 = c1p[0];

    #pragma unroll
    for (int k = 0; k < 8; ++k) {
        const int l = rg * 8 + k;
        float4 xv = *(const float4*)&atom[((size_t)b * L + l0 + l) * D + q * 4];
        float dot = xv.x * vq.x + xv.y * vq.y + xv.z * vq.z + xv.w * vq.w;
        dot += __shfl_xor(dot, 1);  dot += __shfl_xor(dot, 2);
        dot += __shfl_xor(dot, 4);  dot += __shfl_xor(dot, 8);
        dot += __shfl_xor(dot, 16);
        union { ushort us[4]; uint2 u2; } pk;
        pk.us[0] = f2bf(xv.x); pk.us[1] = f2bf(xv.y);
        pk.us[2] = f2bf(xv.z); pk.us[3] = f2bf(xv.w);
        *(uint2*)&Ls[l][q * 4] = pk.u2;
        if (q == 0) {
            float msk = smask[(size_t)b * L + l0 + l];
            sM[(size_t)b * L + l0 + l] = (msk > -0.5f) ? (dot + c1) : -1e30f;
        }
    }
    __syncthreads();
    {   // transposed write-out: thread = (d = tid>>1, h = tid&1)
        const int d = tid >> 1, h = tid & 1;
        #pragma unroll
        for (int jj = 0; jj < 4; ++jj) {
            alignas(16) ushort tmp[8];
            #pragma unroll
            for (int m = 0; m < 8; ++m) tmp[m] = Ls[h * 32 + jj * 8 + m][d];
            *(int4*)&atomT[((size_t)(b * 128 + d) << 10) + l0 + h * 32 + jj * 8] =
                *(int4*)tmp;
        }
    }
}

// ---------------------------------------------------------------------------
// attn v9: block = (b, 32 a-rows), 4 waves; wave w owns d/e-slice [32w,32w+32).
// Same phases as v8, but: (1) batch->XCD mapping matches trans (slab is
// L2-local), (2) afrag pipeline deepened to 8 chunks (16 loads in flight,
// ~400+ cy of cover).
// ---------------------------------------------------------------------------
__global__ __launch_bounds__(256, 2) void attn_kernel(
    const float* __restrict__ molf, const float* __restrict__ amask,
    const ushort* __restrict__ atomT, const float* __restrict__ sM_g,
    const float* __restrict__ u, const float* __restrict__ c0p,
    const ushort* __restrict__ WB, const float* __restrict__ bnb,
    const float* __restrict__ gamma, const float* __restrict__ beta,
    float* __restrict__ out) {
    __shared__ ushort Pl[2][16384];              // 64 KB, planes A/B (TT aliases A)
    __shared__ ushort sLb[1024], eLb[1024], fLb[1024];   // 6 KB bf16 tables
    __shared__ float thL[32], eaL[32], faL[32];
    __shared__ float wmaxL[4];
    __shared__ float psumsL[4][32];
    __shared__ float lnP[4][2][16][2];
    __shared__ float gbL[256];

    const int bid = blockIdx.x;
    const int x = bid & 7, j = bid >> 3;
    const int b  = x + 8 * (j & 7);              // b % 8 == bid % 8 (matches trans)
    const int at = j >> 3;                       // 8 tiles of 32 a-rows
    const int tid = threadIdx.x;
    const int w = tid >> 6, lane = tid & 63;
    const int la = lane & 15, kg = lane >> 4;
    const int xo = la & 7;

    // ---- prologue: first 8 chunks' afrag loads (16 in flight)
    const ushort* atomTb = atomT + (size_t)b * D * L;
    const ushort* pr0 = &atomTb[(size_t)(w * 32 + la) * L + kg * 8];
    const ushort* pr1 = &atomTb[(size_t)(w * 32 + 16 + la) * L + kg * 8];
    bf16x8 a00 = *(const bf16x8*)&pr0[0],   a01 = *(const bf16x8*)&pr1[0];
    bf16x8 a10 = *(const bf16x8*)&pr0[32],  a11 = *(const bf16x8*)&pr1[32];
    bf16x8 a20 = *(const bf16x8*)&pr0[64],  a21 = *(const bf16x8*)&pr1[64];
    bf16x8 a30 = *(const bf16x8*)&pr0[96],  a31 = *(const bf16x8*)&pr1[96];
    bf16x8 a40 = *(const bf16x8*)&pr0[128], a41 = *(const bf16x8*)&pr1[128];
    bf16x8 a50 = *(const bf16x8*)&pr0[160], a51 = *(const bf16x8*)&pr1[160];
    bf16x8 a60 = *(const bf16x8*)&pr0[192], a61 = *(const bf16x8*)&pr1[192];
    bf16x8 a70 = *(const bf16x8*)&pr0[224], a71 = *(const bf16x8*)&pr1[224];

    if (tid < 32)      ((float4*)gbL)[tid] = ((const float4*)gamma)[tid];
    else if (tid < 64) ((float4*)gbL)[tid] = ((const float4*)beta)[tid - 32];

    // ---- phase A0: softmax tables (bf16) + batch max
    {
        const int i4 = tid * 4;
        float4 sa = *(const float4*)&sM_g[(size_t)b * L + i4];
        union { ushort us[4]; uint2 u2; } ps, pe, pf;
        ps.us[0] = f2bf(sa.x); ps.us[1] = f2bf(sa.y);
        ps.us[2] = f2bf(sa.z); ps.us[3] = f2bf(sa.w);
        pe.us[0] = f2bf(__expf(sa.x)); pe.us[1] = f2bf(__expf(sa.y));
        pe.us[2] = f2bf(__expf(sa.z)); pe.us[3] = f2bf(__expf(sa.w));
        pf.us[0] = f2bf(__expf(NEG_SLOPE * sa.x)); pf.us[1] = f2bf(__expf(NEG_SLOPE * sa.y));
        pf.us[2] = f2bf(__expf(NEG_SLOPE * sa.z)); pf.us[3] = f2bf(__expf(NEG_SLOPE * sa.w));
        *(uint2*)&sLb[i4] = ps.u2; *(uint2*)&eLb[i4] = pe.u2; *(uint2*)&fLb[i4] = pf.u2;
        float mx = fmaxf(fmaxf(sa.x, sa.y), fmaxf(sa.z, sa.w));
        #pragma unroll
        for (int o = 1; o < 64; o <<= 1) mx = fmaxf(mx, __shfl_xor(mx, o));
        if (lane == 0) wmaxL[w] = mx;
    }
    __syncthreads();

    // ---- phase B: s_mol + per-row constants (32 rows x 8 threads)
    {
        const float M = fmaxf(fmaxf(wmaxL[0], wmaxL[1]), fmaxf(wmaxL[2], wmaxL[3]));
        const int r = tid >> 3, q = tid & 7;
        const float* xp = molf + ((size_t)b * A + at * 32 + r) * D + q * 16;
        float p = 0.f;
        #pragma unroll
        for (int k = 0; k < 4; ++k) {
            float4 xv = *(const float4*)&xp[k * 4];
            float4 uv = *(const float4*)&u[q * 16 + k * 4];
            p += xv.x * uv.x + xv.y * uv.y + xv.z * uv.z + xv.w * uv.w;
        }
        p += __shfl_xor(p, 1); p += __shfl_xor(p, 2); p += __shfl_xor(p, 4);
        if (q == 0) {
            float sm = p + c0p[0];
            float z = sm + M;
            float m = (z > 0.f) ? z : NEG_SLOPE * z;   // exact row max
            thL[r] = -sm;
            eaL[r] = __expf(sm - m);
            faL[r] = __expf(NEG_SLOPE * sm - m);
        }
    }
    __syncthreads();

    // ---- phase C: P-fill, wave w covers l in [w*256,(w+1)*256), both planes
    float psum0 = 0.f, psum1 = 0.f;
    {
        const float thA = thL[la],      eaA = eaL[la],      faA = faL[la];
        const float thB = thL[la + 16], eaB = eaL[la + 16], faB = faL[la + 16];
        char* PrA = (char*)&Pl[0][0] + la * 2048;
        char* PrB = (char*)&Pl[1][0] + la * 2048;
        #pragma unroll 2
        for (int p5 = 0; p5 < 8; ++p5) {
            const int l0 = w * 256 + p5 * 32 + kg * 8;
            bf16x8 sb = *(const bf16x8*)&sLb[l0];
            bf16x8 eb = *(const bf16x8*)&eLb[l0];
            bf16x8 fb = *(const bf16x8*)&fLb[l0];
            union { ushort us[8]; int4 v; } pkA, pkB;
            #pragma unroll
            for (int jj = 0; jj < 8; ++jj) {
                float s = bf2f((ushort)sb[jj]);
                float e = bf2f((ushort)eb[jj]);
                float f = bf2f((ushort)fb[jj]);
                float pA = (s > thA) ? eaA * e : faA * f;
                float pB = (s > thB) ? eaB * e : faB * f;
                psum0 += pA; psum1 += pB;
                pkA.us[jj] = f2bf(pA); pkB.us[jj] = f2bf(pB);
            }
            const int slot = ((w * 32 + p5 * 4 + kg) ^ xo) * 16;
            *(int4*)(PrA + slot) = pkA.v;
            *(int4*)(PrB + slot) = pkB.v;
        }
    }
    psum0 += __shfl_xor(psum0, 16); psum0 += __shfl_xor(psum0, 32);
    psum1 += __shfl_xor(psum1, 16); psum1 += __shfl_xor(psum1, 32);
    if (lane < 16) { psumsL[w][la] = psum0; psumsL[w][la + 16] = psum1; }
    __syncthreads();

    // ---- phase D: PV main loop (no barriers, 8-deep named-register pipeline)
    const char* PbA = (const char*)&Pl[0][0] + la * 2048;
    const char* PbB = (const char*)&Pl[1][0] + la * 2048;
#define LDPA(I_) (*(const bf16x8*)(PbA + ((((I_) * 4 + kg) ^ xo) * 16)))
#define LDPB(I_) (*(const bf16x8*)(PbB + ((((I_) * 4 + kg) ^ xo) * 16)))
    f32x4 acc0a = {}, acc1a = {}, acc0b = {}, acc1b = {};
#define STEP(S0_, S1_, I_)                                                     \
    {                                                                          \
        bf16x8 bA = LDPA(I_); bf16x8 bB = LDPB(I_);                            \
        acc0a = __builtin_amdgcn_mfma_f32_16x16x32_bf16(S0_, bA, acc0a, 0, 0, 0); \
        acc1a = __builtin_amdgcn_mfma_f32_16x16x32_bf16(S1_, bA, acc1a, 0, 0, 0); \
        acc0b = __builtin_amdgcn_mfma_f32_16x16x32_bf16(S0_, bB, acc0b, 0, 0, 0); \
        acc1b = __builtin_amdgcn_mfma_f32_16x16x32_bf16(S1_, bB, acc1b, 0, 0, 0); \
        if ((I_) < 24) { S0_ = *(const bf16x8*)&pr0[((I_) + 8) * 32];          \
                         S1_ = *(const bf16x8*)&pr1[((I_) + 8) * 32]; }        \
    }
#define GROUP(I_)                                                              \
    STEP(a00, a01, (I_) + 0) STEP(a10, a11, (I_) + 1)                          \
    STEP(a20, a21, (I_) + 2) STEP(a30, a31, (I_) + 3)                          \
    STEP(a40, a41, (I_) + 4) STEP(a50, a51, (I_) + 5)                          \
    STEP(a60, a61, (I_) + 6) STEP(a70, a71, (I_) + 7)
    GROUP(0) GROUP(8) GROUP(16) GROUP(24)
#undef GROUP
#undef STEP
#undef LDPA
#undef LDPB

    // ---- prefetch ctx-GEMM operands before the barrier
    bf16x8 wb0[4], wb1[4];
    {
        const ushort* wr0 = WB + (size_t)((2 * w) * 16 + la) * D + kg * 8;
        const ushort* wr1 = WB + (size_t)((2 * w + 1) * 16 + la) * D + kg * 8;
        #pragma unroll
        for (int ks = 0; ks < 4; ++ks) {
            wb0[ks] = *(const bf16x8*)&wr0[ks * 32];
            wb1[ks] = *(const bf16x8*)&wr1[ks * 32];
        }
    }
    float4 bias0 = *(const float4*)&bnb[w * 32 + kg * 4];
    float4 bias1 = *(const float4*)&bnb[w * 32 + 16 + kg * 4];
    const float amA = amask[(size_t)b * A + at * 32 + la];
    const float amB = amask[(size_t)b * A + at * 32 + 16 + la];
    __syncthreads();   // all Pl reads done -> safe to alias TT onto plane A

    // ---- phase E: bounce T (bf16) into TT[32][128] (XOR-swizzled chunks)
    {
        ushort* TT = &Pl[0][0];
        const int ch0 = w * 4 + (kg >> 1);
        const int ch1 = ch0 + 2;
        const int sub = (kg & 1) * 8;
        union { ushort us[4]; uint2 u2; } k0, k1;
        #pragma unroll
        for (int r = 0; r < 4; ++r) { k0.us[r] = f2bf(acc0a[r]); k1.us[r] = f2bf(acc1a[r]); }
        *(uint2*)((char*)TT + la * 256 + ((ch0 ^ xo) * 16) + sub) = k0.u2;
        *(uint2*)((char*)TT + la * 256 + ((ch1 ^ xo) * 16) + sub) = k1.u2;
        #pragma unroll
        for (int r = 0; r < 4; ++r) { k0.us[r] = f2bf(acc0b[r]); k1.us[r] = f2bf(acc1b[r]); }
        *(uint2*)((char*)TT + (la + 16) * 256 + ((ch0 ^ xo) * 16) + sub) = k0.u2;
        *(uint2*)((char*)TT + (la + 16) * 256 + ((ch1 ^ xo) * 16) + sub) = k1.u2;
    }
    __syncthreads();

    // ---- phase F: ctx = T.W (16 MFMA/wave) + LayerNorm
    const ushort* TT = &Pl[0][0];
#define LDT(ROW_, KS_) (*(const bf16x8*)((const char*)TT + (ROW_) * 256 + \
                         ((((KS_) * 4 + kg) ^ xo) * 16)))
    f32x4 cA0 = {}, cA1 = {}, cB0 = {}, cB1 = {};
    #pragma unroll
    for (int ks = 0; ks < 4; ++ks) {
        bf16x8 tA = LDT(la, ks);
        bf16x8 tB = LDT(la + 16, ks);
        cA0 = __builtin_amdgcn_mfma_f32_16x16x32_bf16(wb0[ks], tA, cA0, 0, 0, 0);
        cA1 = __builtin_amdgcn_mfma_f32_16x16x32_bf16(wb1[ks], tA, cA1, 0, 0, 0);
        cB0 = __builtin_amdgcn_mfma_f32_16x16x32_bf16(wb0[ks], tB, cB0, 0, 0, 0);
        cB1 = __builtin_amdgcn_mfma_f32_16x16x32_bf16(wb1[ks], tB, cB1, 0, 0, 0);
    }
#undef LDT

    const float psA = psumsL[0][la] + psumsL[1][la] + psumsL[2][la] + psumsL[3][la];
    const float psB = psumsL[0][la + 16] + psumsL[1][la + 16]
                    + psumsL[2][la + 16] + psumsL[3][la + 16];
    const float scA = amA / psA, scB = amB / psB;
    float xA[8], xB[8];
    float s1A = 0.f, s2A = 0.f, s1B = 0.f, s2B = 0.f;
    const float* bp0 = (const float*)&bias0;
    const float* bp1 = (const float*)&bias1;
    #pragma unroll
    for (int r = 0; r < 4; ++r) {
        xA[r]     = cA0[r] * scA + amA * bp0[r];
        xA[4 + r] = cA1[r] * scA + amA * bp1[r];
        xB[r]     = cB0[r] * scB + amB * bp0[r];
        xB[4 + r] = cB1[r] * scB + amB * bp1[r];
        s1A += xA[r] + xA[4 + r]; s2A += xA[r] * xA[r] + xA[4 + r] * xA[4 + r];
        s1B += xB[r] + xB[4 + r]; s2B += xB[r] * xB[r] + xB[4 + r] * xB[4 + r];
    }
    s1A += __shfl_xor(s1A, 16); s1A += __shfl_xor(s1A, 32);
    s2A += __shfl_xor(s2A, 16); s2A += __shfl_xor(s2A, 32);
    s1B += __shfl_xor(s1B, 16); s1B += __shfl_xor(s1B, 32);
    s2B += __shfl_xor(s2B, 16); s2B += __shfl_xor(s2B, 32);
    if (lane < 16) {
        lnP[w][0][la][0] = s1A; lnP[w][0][la][1] = s2A;
        lnP[w][1][la][0] = s1B; lnP[w][1][la][1] = s2B;
    }
    __syncthreads();
    const float S1A = lnP[0][0][la][0] + lnP[1][0][la][0] + lnP[2][0][la][0] + lnP[3][0][la][0];
    const float S2A = lnP[0][0][la][1] + lnP[1][0][la][1] + lnP[2][0][la][1] + lnP[3][0][la][1];
    const float S1B = lnP[0][1][la][0] + lnP[1][1][la][0] + lnP[2][1][la][0] + lnP[3][1][la][0];
    const float S2B = lnP[0][1][la][1] + lnP[1][1][la][1] + lnP[2][1][la][1] + lnP[3][1][la][1];
    const float muA = S1A * (1.f / 128.f);
    const float rsA = rsqrtf(S2A * (1.f / 128.f) - muA * muA + LN_EPS);
    const float muB = S1B * (1.f / 128.f);
    const float rsB = rsqrtf(S2B * (1.f / 128.f) - muB * muB + LN_EPS);
    const size_t oA = ((size_t)b * A + at * 32 + la) * D;
    const size_t oB = ((size_t)b * A + at * 32 + 16 + la) * D;
    #pragma unroll
    for (int t = 0; t < 2; ++t) {
        const int e0 = w * 32 + t * 16 + kg * 4;
        float4 g4 = *(float4*)&gbL[e0];
        float4 b4 = *(float4*)&gbL[128 + e0];
        float4 ovA, ovB;
        const float* xpA = &xA[t * 4];
        const float* xpB = &xB[t * 4];
        ((float*)&ovA)[0] = (xpA[0] - muA) * rsA * g4.x + b4.x;
        ((float*)&ovA)[1] = (xpA[1] - muA) * rsA * g4.y + b4.y;
        ((float*)&ovA)[2] = (xpA[2] - muA) * rsA * g4.z + b4.z;
        ((float*)&ovA)[3] = (xpA[3] - muA) * rsA * g4.w + b4.w;
        ((float*)&ovB)[0] = (xpB[0] - muB) * rsB * g4.x + b4.x;
        ((float*)&ovB)[1] = (xpB[1] - muB) * rsB * g4.y + b4.y;
        ((float*)&ovB)[2] = (xpB[2] - muB) * rsB * g4.z + b4.z;
        ((float*)&ovB)[3] = (xpB[3] - muB) * rsB * g4.w + b4.w;
        *(float4*)&out[oA + e0] = ovA;
        *(float4*)&out[oB + e0] = ovB;
    }
}

// ---------------------------------------------------------------------------
extern "C" void kernel_launch(void* const* d_in, const int* in_sizes, int n_in,
                              void* d_out, int out_size, void* d_ws, size_t ws_size,
                              hipStream_t stream) {
    const float* molf  = (const float*)d_in[0];
    const float* atomf = (const float*)d_in[1];
    const float* amask = (const float*)d_in[2];
    const float* smask = (const float*)d_in[3];
    const float* W_mol = (const float*)d_in[4];
    const float* b_mol = (const float*)d_in[5];
    const float* W_nb  = (const float*)d_in[6];
    const float* b_nb  = (const float*)d_in[7];
    const float* w_am  = (const float*)d_in[8];
    const float* w_aa  = (const float*)d_in[9];
    const float* b_al  = (const float*)d_in[10];
    const float* gamma = (const float*)d_in[11];
    const float* beta  = (const float*)d_in[12];
    float* out = (float*)d_out;

    // ws: atomT bf16 [B*D*L] | sM [B*L] | u,v [D] | c0,c1 | WB bf16 [D*D]
    ushort* atomT = (ushort*)d_ws;
    float* sM     = (float*)(atomT + (size_t)B * D * L);
    float* u_ws   = sM + (size_t)B * L;
    float* v_ws   = u_ws + D;
    float* c0_ws  = v_ws + D;
    float* c1_ws  = c0_ws + 1;
    ushort* WB    = (ushort*)(c1_ws + 1);

    prep_kernel<<<128, 128, 0, stream>>>(W_mol, b_mol, w_am, b_al, W_nb, b_nb,
                                         w_aa, u_ws, v_ws, c0_ws, c1_ws, WB);
    trans_kernel<<<(B * L) / 64, 256, 0, stream>>>(atomf, v_ws, c1_ws, smask,
                                                   atomT, sM);
    attn_kernel<<<B * (A / 32), 256, 0, stream>>>(molf, amask, atomT, sM, u_ws,
                                                  c0_ws, WB, b_nb, gamma, beta, out);
}

// Round 9
// 46.011 us; speedup vs baseline: 6.4636x; 1.0621x over previous
//
#include <hip/hip_runtime.h>
#include <hip/hip_bf16.h>
#include <math.h>

#define NEG_SLOPE 0.2f
#define LN_EPS 1e-5f

constexpr int B = 64, A = 256, L = 1024, D = 128;

typedef float f32x4 __attribute__((ext_vector_type(4)));
typedef short bf16x8 __attribute__((ext_vector_type(8)));

__device__ __forceinline__ ushort f2bf(float x) {
    __hip_bfloat16 h = __float2bfloat16(x);
    return *reinterpret_cast<ushort*>(&h);
}
__device__ __forceinline__ float bf2f(ushort x) {
    unsigned u = ((unsigned)x) << 16;
    return __uint_as_float(u);
}

// ---------------------------------------------------------------------------
// prep: u = W_mol@w_am, v = W_nb@w_aa, c0 = b_mol.w_am + b_al, c1 = b_nb.w_aa,
//       WB[e][d] = bf16(W_nb[d][e])
// ---------------------------------------------------------------------------
__global__ void prep_kernel(const float* __restrict__ Wmol, const float* __restrict__ bmol,
                            const float* __restrict__ wam, const float* __restrict__ bal,
                            const float* __restrict__ Wnb, const float* __restrict__ bnb,
                            const float* __restrict__ waa,
                            float* __restrict__ u, float* __restrict__ v,
                            float* __restrict__ c0, float* __restrict__ c1,
                            ushort* __restrict__ WB) {
    __shared__ float redU[2], redV[2], redC0[2], redC1[2];
    const int i = blockIdx.x, e = threadIdx.x;
    const int lane = e & 63, wv = e >> 6;
    float wnb_ie = Wnb[i * D + e];
    WB[e * D + i] = f2bf(wnb_ie);
    float pu = Wmol[i * D + e] * wam[e];
    float pv = wnb_ie * waa[e];
    float q0 = (i == 0) ? bmol[e] * wam[e] : 0.f;
    float q1 = (i == 0) ? bnb[e] * waa[e] : 0.f;
    #pragma unroll
    for (int o = 1; o < 64; o <<= 1) {
        pu += __shfl_xor(pu, o); pv += __shfl_xor(pv, o);
        q0 += __shfl_xor(q0, o); q1 += __shfl_xor(q1, o);
    }
    if (lane == 0) { redU[wv] = pu; redV[wv] = pv; redC0[wv] = q0; redC1[wv] = q1; }
    __syncthreads();
    if (e == 0) {
        u[i] = redU[0] + redU[1];
        v[i] = redV[0] + redV[1];
        if (i == 0) { c0[0] = redC0[0] + redC0[1] + bal[0];
                      c1[0] = redC1[0] + redC1[1]; }
    }
}

// ---------------------------------------------------------------------------
// trans: atom fp32 -> atomT bf16 [b][d][l] + masked s_atm tables base
// ---------------------------------------------------------------------------
__global__ __launch_bounds__(256) void trans_kernel(
    const float* __restrict__ atom, const float* __restrict__ v,
    const float* __restrict__ c1p, const float* __restrict__ smask,
    ushort* __restrict__ atomT, float* __restrict__ sM) {
    __shared__ ushort Ls[64][132];
    const int tid = threadIdx.x;
    const int q = tid & 31, rg = tid >> 5;
    const int bidx = blockIdx.x;
    const int x = bidx & 7, j = bidx >> 3;
    const int b = x + 8 * (j & 7);
    const int l0 = (j >> 3) * 64;
    const float4 vq = *(const float4*)&v[q * 4];
    const float c1 = c1p[0];

    #pragma unroll
    for (int k = 0; k < 8; ++k) {
        const int l = rg * 8 + k;
        float4 xv = *(const float4*)&atom[((size_t)b * L + l0 + l) * D + q * 4];
        float dot = xv.x * vq.x + xv.y * vq.y + xv.z * vq.z + xv.w * vq.w;
        dot += __shfl_xor(dot, 1);  dot += __shfl_xor(dot, 2);
        dot += __shfl_xor(dot, 4);  dot += __shfl_xor(dot, 8);
        dot += __shfl_xor(dot, 16);
        union { ushort us[4]; uint2 u2; } pk;
        pk.us[0] = f2bf(xv.x); pk.us[1] = f2bf(xv.y);
        pk.us[2] = f2bf(xv.z); pk.us[3] = f2bf(xv.w);
        *(uint2*)&Ls[l][q * 4] = pk.u2;
        if (q == 0) {
            float msk = smask[(size_t)b * L + l0 + l];
            sM[(size_t)b * L + l0 + l] = (msk > -0.5f) ? (dot + c1) : -1e30f;
        }
    }
    __syncthreads();
    {
        const int d = tid >> 1, h = tid & 1;
        #pragma unroll
        for (int jj = 0; jj < 4; ++jj) {
            alignas(16) ushort tmp[8];
            #pragma unroll
            for (int m = 0; m < 8; ++m) tmp[m] = Ls[h * 32 + jj * 8 + m][d];
            *(int4*)&atomT[((size_t)(b * 128 + d) << 10) + l0 + h * 32 + jj * 8] =
                *(int4*)tmp;
        }
    }
}

// ---------------------------------------------------------------------------
// attn v10: block = (b, 32 a-rows), 4 waves (wa = w&1: a-16-slice,
// wd = w>>1: d-64-half). 8 l-tiles of 128: burst-load tile (8x16B/thread)
// -> LDS [128][136] padded -> bfrag-from-tables + 16 MFMA/wave, 1 barrier
// per tile (2-phase schedule; loads fly during previous tile's compute).
// Epilogue: T -> TT bounce + ctx = W.T GEMM + LayerNorm (R7-verified).
// ---------------------------------------------------------------------------
__global__ __launch_bounds__(256, 2) void attn_kernel(
    const float* __restrict__ molf, const float* __restrict__ amask,
    const ushort* __restrict__ atomT, const float* __restrict__ sM_g,
    const float* __restrict__ u, const float* __restrict__ c0p,
    const ushort* __restrict__ WB, const float* __restrict__ bnb,
    const float* __restrict__ gamma, const float* __restrict__ beta,
    float* __restrict__ out) {
    __shared__ ushort TlA[128][136], TlB[128][136];      // 69.6 KB tiles
    __shared__ ushort sLb[1024], eLb[1024], fLb[1024];   // 6 KB bf16 tables
    __shared__ float thL[32], eaL[32], faL[32];
    __shared__ float wmaxL[4];
    __shared__ float psumsL[32];
    __shared__ float lnP[4][2][16][2];
    __shared__ float gbL[256];

    const int bid = blockIdx.x;
    const int lid = (bid & 7) * 64 + (bid >> 3);   // XCD-bijective (512 % 8 == 0)
    const int b  = lid >> 3;
    const int at = lid & 7;
    const int tid = threadIdx.x;
    const int w = tid >> 6, lane = tid & 63;
    const int la = lane & 15, kg = lane >> 4;
    const int xo = la & 7;
    const int wa = w & 1, wd = w >> 1;
    const int c = tid & 15, dlo = tid >> 4;        // staging map

    const ushort* atomTb = atomT + (size_t)b * D * L;
    int4 R0r, R1r, R2r, R3r, R4r, R5r, R6r, R7r;

#define LOADG(T_)                                                              \
    {                                                                          \
        const ushort* src_ = atomTb + (size_t)dlo * L + (T_) * 128 + c * 8;    \
        R0r = *(const int4*)(src_ + 0 * 16 * L);                               \
        R1r = *(const int4*)(src_ + 1 * 16 * L);                               \
        R2r = *(const int4*)(src_ + 2 * 16 * L);                               \
        R3r = *(const int4*)(src_ + 3 * 16 * L);                               \
        R4r = *(const int4*)(src_ + 4 * 16 * L);                               \
        R5r = *(const int4*)(src_ + 5 * 16 * L);                               \
        R6r = *(const int4*)(src_ + 6 * 16 * L);                               \
        R7r = *(const int4*)(src_ + 7 * 16 * L);                               \
    }
#define WLDS(BUF_)                                                             \
    {                                                                          \
        *(int4*)&BUF_[0 * 16 + dlo][c * 8] = R0r;                              \
        *(int4*)&BUF_[1 * 16 + dlo][c * 8] = R1r;                              \
        *(int4*)&BUF_[2 * 16 + dlo][c * 8] = R2r;                              \
        *(int4*)&BUF_[3 * 16 + dlo][c * 8] = R3r;                              \
        *(int4*)&BUF_[4 * 16 + dlo][c * 8] = R4r;                              \
        *(int4*)&BUF_[5 * 16 + dlo][c * 8] = R5r;                              \
        *(int4*)&BUF_[6 * 16 + dlo][c * 8] = R6r;                              \
        *(int4*)&BUF_[7 * 16 + dlo][c * 8] = R7r;                              \
    }

    LOADG(0)   // tile 0 in flight under phases A0/B

    if (tid < 32)      ((float4*)gbL)[tid] = ((const float4*)gamma)[tid];
    else if (tid < 64) ((float4*)gbL)[tid] = ((const float4*)beta)[tid - 32];

    // ---- phase A0: softmax tables (bf16) + batch max
    {
        const int i4 = tid * 4;
        float4 sa = *(const float4*)&sM_g[(size_t)b * L + i4];
        union { ushort us[4]; uint2 u2; } ps, pe, pf;
        ps.us[0] = f2bf(sa.x); ps.us[1] = f2bf(sa.y);
        ps.us[2] = f2bf(sa.z); ps.us[3] = f2bf(sa.w);
        pe.us[0] = f2bf(__expf(sa.x)); pe.us[1] = f2bf(__expf(sa.y));
        pe.us[2] = f2bf(__expf(sa.z)); pe.us[3] = f2bf(__expf(sa.w));
        pf.us[0] = f2bf(__expf(NEG_SLOPE * sa.x)); pf.us[1] = f2bf(__expf(NEG_SLOPE * sa.y));
        pf.us[2] = f2bf(__expf(NEG_SLOPE * sa.z)); pf.us[3] = f2bf(__expf(NEG_SLOPE * sa.w));
        *(uint2*)&sLb[i4] = ps.u2; *(uint2*)&eLb[i4] = pe.u2; *(uint2*)&fLb[i4] = pf.u2;
        float mx = fmaxf(fmaxf(sa.x, sa.y), fmaxf(sa.z, sa.w));
        #pragma unroll
        for (int o = 1; o < 64; o <<= 1) mx = fmaxf(mx, __shfl_xor(mx, o));
        if (lane == 0) wmaxL[w] = mx;
    }
    __syncthreads();

    // ---- phase B: s_mol + per-row softmax constants (32 rows x 8 threads)
    {
        const float M = fmaxf(fmaxf(wmaxL[0], wmaxL[1]), fmaxf(wmaxL[2], wmaxL[3]));
        const int r = tid >> 3, q = tid & 7;
        const float* xp = molf + ((size_t)b * A + at * 32 + r) * D + q * 16;
        float p = 0.f;
        #pragma unroll
        for (int k = 0; k < 4; ++k) {
            float4 xv = *(const float4*)&xp[k * 4];
            float4 uv = *(const float4*)&u[q * 16 + k * 4];
            p += xv.x * uv.x + xv.y * uv.y + xv.z * uv.z + xv.w * uv.w;
        }
        p += __shfl_xor(p, 1); p += __shfl_xor(p, 2); p += __shfl_xor(p, 4);
        if (q == 0) {
            float sm = p + c0p[0];
            float z = sm + M;
            float m = (z > 0.f) ? z : NEG_SLOPE * z;
            thL[r] = -sm;
            eaL[r] = __expf(sm - m);
            faL[r] = __expf(NEG_SLOPE * sm - m);
        }
    }
    __syncthreads();

    const float thW = thL[wa * 16 + la];
    const float eaW = eaL[wa * 16 + la];
    const float faW = faL[wa * 16 + la];
    f32x4 acc0 = {}, acc1 = {}, acc2 = {}, acc3 = {};
    float psum = 0.f;

    WLDS(TlA)
    LOADG(1)
    __syncthreads();

#define COMPUTE(BUF_, T_)                                                      \
    {                                                                          \
        _Pragma("unroll")                                                      \
        for (int ks = 0; ks < 4; ++ks) {                                       \
            const int lb_ = (T_) * 128 + ks * 32 + kg * 8;                     \
            bf16x8 sb = *(const bf16x8*)&sLb[lb_];                             \
            bf16x8 eb = *(const bf16x8*)&eLb[lb_];                             \
            bf16x8 fb = *(const bf16x8*)&fLb[lb_];                             \
            bf16x8 bfrag;                                                      \
            _Pragma("unroll")                                                  \
            for (int jj = 0; jj < 8; ++jj) {                                   \
                float s_ = bf2f((ushort)sb[jj]);                               \
                float e_ = bf2f((ushort)eb[jj]);                               \
                float f_ = bf2f((ushort)fb[jj]);                               \
                float p_ = (s_ > thW) ? eaW * e_ : faW * f_;                   \
                psum += p_;                                                    \
                bfrag[jj] = (short)f2bf(p_);                                   \
            }                                                                  \
            const int col_ = ks * 32 + kg * 8;                                 \
            bf16x8 a0_ = *(const bf16x8*)&BUF_[wd * 64 + 0 * 16 + la][col_];   \
            bf16x8 a1_ = *(const bf16x8*)&BUF_[wd * 64 + 1 * 16 + la][col_];   \
            bf16x8 a2_ = *(const bf16x8*)&BUF_[wd * 64 + 2 * 16 + la][col_];   \
            bf16x8 a3_ = *(const bf16x8*)&BUF_[wd * 64 + 3 * 16 + la][col_];   \
            acc0 = __builtin_amdgcn_mfma_f32_16x16x32_bf16(a0_, bfrag, acc0, 0, 0, 0); \
            acc1 = __builtin_amdgcn_mfma_f32_16x16x32_bf16(a1_, bfrag, acc1, 0, 0, 0); \
            acc2 = __builtin_amdgcn_mfma_f32_16x16x32_bf16(a2_, bfrag, acc2, 0, 0, 0); \
            acc3 = __builtin_amdgcn_mfma_f32_16x16x32_bf16(a3_, bfrag, acc3, 0, 0, 0); \
        }                                                                      \
    }

    COMPUTE(TlA, 0) WLDS(TlB) LOADG(2) __syncthreads();
    COMPUTE(TlB, 1) WLDS(TlA) LOADG(3) __syncthreads();
    COMPUTE(TlA, 2) WLDS(TlB) LOADG(4) __syncthreads();
    COMPUTE(TlB, 3) WLDS(TlA) LOADG(5) __syncthreads();
    COMPUTE(TlA, 4) WLDS(TlB) LOADG(6) __syncthreads();
    COMPUTE(TlB, 5) WLDS(TlA) LOADG(7) __syncthreads();
    COMPUTE(TlA, 6) WLDS(TlB)

    // prefetch ctx-GEMM operands before the last tile barrier
    bf16x8 wb0[4], wb1[4];
    {
        const ushort* wr0 = WB + (size_t)((2 * w) * 16 + la) * D + kg * 8;
        const ushort* wr1 = WB + (size_t)((2 * w + 1) * 16 + la) * D + kg * 8;
        #pragma unroll
        for (int ks = 0; ks < 4; ++ks) {
            wb0[ks] = *(const bf16x8*)&wr0[ks * 32];
            wb1[ks] = *(const bf16x8*)&wr1[ks * 32];
        }
    }
    float4 bias0 = *(const float4*)&bnb[w * 32 + kg * 4];
    float4 bias1 = *(const float4*)&bnb[w * 32 + 16 + kg * 4];
    const float amA = amask[(size_t)b * A + at * 32 + la];
    const float amB = amask[(size_t)b * A + at * 32 + 16 + la];
    __syncthreads();
    COMPUTE(TlB, 7)
#undef COMPUTE
#undef WLDS
#undef LOADG

    // psum: full row sum (each wave covered all l); publish from wd==0
    psum += __shfl_xor(psum, 16);
    psum += __shfl_xor(psum, 32);
    if (wd == 0 && lane < 16) psumsL[wa * 16 + la] = psum;

    // ---- phase E: bounce T (bf16) into TT[32][128] (chunk-XOR swizzled)
    {
        ushort* TT = &TlA[0][0];
        const int row = wa * 16 + la;
        const int chb = wd * 8 + (kg >> 1);
        const int sub = (kg & 1) * 8;
        union { ushort us[4]; uint2 u2; } k0;
        #pragma unroll
        for (int dt = 0; dt < 4; ++dt) {
            f32x4 av = (dt == 0) ? acc0 : (dt == 1) ? acc1 : (dt == 2) ? acc2 : acc3;
            k0.us[0] = f2bf(av[0]); k0.us[1] = f2bf(av[1]);
            k0.us[2] = f2bf(av[2]); k0.us[3] = f2bf(av[3]);
            const int ch = chb + dt * 2;
            *(uint2*)((char*)TT + row * 256 + ((ch ^ xo) * 16) + sub) = k0.u2;
        }
    }
    __syncthreads();

    // ---- phase F: ctx = T.W (16 MFMA/wave) + LayerNorm  (R7-verified)
    const ushort* TT = &TlA[0][0];
#define LDT(ROW_, KS_) (*(const bf16x8*)((const char*)TT + (ROW_) * 256 + \
                         ((((KS_) * 4 + kg) ^ xo) * 16)))
    f32x4 cA0 = {}, cA1 = {}, cB0 = {}, cB1 = {};
    #pragma unroll
    for (int ks = 0; ks < 4; ++ks) {
        bf16x8 tA = LDT(la, ks);
        bf16x8 tB = LDT(la + 16, ks);
        cA0 = __builtin_amdgcn_mfma_f32_16x16x32_bf16(wb0[ks], tA, cA0, 0, 0, 0);
        cA1 = __builtin_amdgcn_mfma_f32_16x16x32_bf16(wb1[ks], tA, cA1, 0, 0, 0);
        cB0 = __builtin_amdgcn_mfma_f32_16x16x32_bf16(wb0[ks], tB, cB0, 0, 0, 0);
        cB1 = __builtin_amdgcn_mfma_f32_16x16x32_bf16(wb1[ks], tB, cB1, 0, 0, 0);
    }
#undef LDT

    const float psA = psumsL[la];
    const float psB = psumsL[la + 16];
    const float scA = amA / psA, scB = amB / psB;
    float xA[8], xB[8];
    float s1A = 0.f, s2A = 0.f, s1B = 0.f, s2B = 0.f;
    const float* bp0 = (const float*)&bias0;
    const float* bp1 = (const float*)&bias1;
    #pragma unroll
    for (int r = 0; r < 4; ++r) {
        xA[r]     = cA0[r] * scA + amA * bp0[r];
        xA[4 + r] = cA1[r] * scA + amA * bp1[r];
        xB[r]     = cB0[r] * scB + amB * bp0[r];
        xB[4 + r] = cB1[r] * scB + amB * bp1[r];
        s1A += xA[r] + xA[4 + r]; s2A += xA[r] * xA[r] + xA[4 + r] * xA[4 + r];
        s1B += xB[r] + xB[4 + r]; s2B += xB[r] * xB[r] + xB[4 + r] * xB[4 + r];
    }
    s1A += __shfl_xor(s1A, 16); s1A += __shfl_xor(s1A, 32);
    s2A += __shfl_xor(s2A, 16); s2A += __shfl_xor(s2A, 32);
    s1B += __shfl_xor(s1B, 16); s1B += __shfl_xor(s1B, 32);
    s2B += __shfl_xor(s2B, 16); s2B += __shfl_xor(s2B, 32);
    if (lane < 16) {
        lnP[w][0][la][0] = s1A; lnP[w][0][la][1] = s2A;
        lnP[w][1][la][0] = s1B; lnP[w][1][la][1] = s2B;
    }
    __syncthreads();
    const float S1A = lnP[0][0][la][0] + lnP[1][0][la][0] + lnP[2][0][la][0] + lnP[3][0][la][0];
    const float S2A = lnP[0][0][la][1] + lnP[1][0][la][1] + lnP[2][0][la][1] + lnP[3][0][la][1];
    const float S1B = lnP[0][1][la][0] + lnP[1][1][la][0] + lnP[2][1][la][0] + lnP[3][1][la][0];
    const float S2B = lnP[0][1][la][1] + lnP[1][1][la][1] + lnP[2][1][la][1] + lnP[3][1][la][1];
    const float muA = S1A * (1.f / 128.f);
    const float rsA = rsqrtf(S2A * (1.f / 128.f) - muA * muA + LN_EPS);
    const float muB = S1B * (1.f / 128.f);
    const float rsB = rsqrtf(S2B * (1.f / 128.f) - muB * muB + LN_EPS);
    const size_t oA = ((size_t)b * A + at * 32 + la) * D;
    const size_t oB = ((size_t)b * A + at * 32 + 16 + la) * D;
    #pragma unroll
    for (int t = 0; t < 2; ++t) {
        const int e0 = w * 32 + t * 16 + kg * 4;
        float4 g4 = *(float4*)&gbL[e0];
        float4 b4 = *(float4*)&gbL[128 + e0];
        float4 ovA, ovB;
        const float* xpA = &xA[t * 4];
        const float* xpB = &xB[t * 4];
        ((float*)&ovA)[0] = (xpA[0] - muA) * rsA * g4.x + b4.x;
        ((float*)&ovA)[1] = (xpA[1] - muA) * rsA * g4.y + b4.y;
        ((float*)&ovA)[2] = (xpA[2] - muA) * rsA * g4.z + b4.z;
        ((float*)&ovA)[3] = (xpA[3] - muA) * rsA * g4.w + b4.w;
        ((float*)&ovB)[0] = (xpB[0] - muB) * rsB * g4.x + b4.x;
        ((float*)&ovB)[1] = (xpB[1] - muB) * rsB * g4.y + b4.y;
        ((float*)&ovB)[2] = (xpB[2] - muB) * rsB * g4.z + b4.z;
        ((float*)&ovB)[3] = (xpB[3] - muB) * rsB * g4.w + b4.w;
        *(float4*)&out[oA + e0] = ovA;
        *(float4*)&out[oB + e0] = ovB;
    }
}

// ---------------------------------------------------------------------------
extern "C" void kernel_launch(void* const* d_in, const int* in_sizes, int n_in,
                              void* d_out, int out_size, void* d_ws, size_t ws_size,
                              hipStream_t stream) {
    const float* molf  = (const float*)d_in[0];
    const float* atomf = (const float*)d_in[1];
    const float* amask = (const float*)d_in[2];
    const float* smask = (const float*)d_in[3];
    const float* W_mol = (const float*)d_in[4];
    const float* b_mol = (const float*)d_in[5];
    const float* W_nb  = (const float*)d_in[6];
    const float* b_nb  = (const float*)d_in[7];
    const float* w_am  = (const float*)d_in[8];
    const float* w_aa  = (const float*)d_in[9];
    const float* b_al  = (const float*)d_in[10];
    const float* gamma = (const float*)d_in[11];
    const float* beta  = (const float*)d_in[12];
    float* out = (float*)d_out;

    // ws: atomT bf16 [B*D*L] | sM [B*L] | u,v [D] | c0,c1 | WB bf16 [D*D]
    ushort* atomT = (ushort*)d_ws;
    float* sM     = (float*)(atomT + (size_t)B * D * L);
    float* u_ws   = sM + (size_t)B * L;
    float* v_ws   = u_ws + D;
    float* c0_ws  = v_ws + D;
    float* c1_ws  = c0_ws + 1;
    ushort* WB    = (ushort*)(c1_ws + 1);

    prep_kernel<<<128, 128, 0, stream>>>(W_mol, b_mol, w_am, b_al, W_nb, b_nb,
                                         w_aa, u_ws, v_ws, c0_ws, c1_ws, WB);
    trans_kernel<<<(B * L) / 64, 256, 0, stream>>>(atomf, v_ws, c1_ws, smask,
                                                   atomT, sM);
    attn_kernel<<<B * (A / 32), 256, 0, stream>>>(molf, amask, atomT, sM, u_ws,
                                                  c0_ws, WB, b_nb, gamma, beta, out);
}

// Round 10
// 44.280 us; speedup vs baseline: 6.7163x; 1.0391x over previous
//
#include <hip/hip_runtime.h>
#include <hip/hip_bf16.h>
#include <math.h>

#define NEG_SLOPE 0.2f
#define LN_EPS 1e-5f

constexpr int B = 64, A = 256, L = 1024, D = 128;

typedef float f32x4 __attribute__((ext_vector_type(4)));
typedef float f32x16 __attribute__((ext_vector_type(16)));
typedef short bf16x8 __attribute__((ext_vector_type(8)));

__device__ __forceinline__ ushort f2bf(float x) {
    __hip_bfloat16 h = __float2bfloat16(x);
    return *reinterpret_cast<ushort*>(&h);
}
__device__ __forceinline__ float bf2f(ushort x) {
    unsigned u = ((unsigned)x) << 16;
    return __uint_as_float(u);
}
__device__ __forceinline__ void gl_lds16(const void* g, void* l) {
    __builtin_amdgcn_global_load_lds(
        (const __attribute__((address_space(1))) unsigned int*)g,
        (__attribute__((address_space(3))) unsigned int*)l, 16, 0, 0);
}

// ---------------------------------------------------------------------------
// prep: u = W_mol@w_am, v = W_nb@w_aa, c0 = b_mol.w_am + b_al, c1 = b_nb.w_aa,
//       WB[e][d] = bf16(W_nb[d][e])
// ---------------------------------------------------------------------------
__global__ void prep_kernel(const float* __restrict__ Wmol, const float* __restrict__ bmol,
                            const float* __restrict__ wam, const float* __restrict__ bal,
                            const float* __restrict__ Wnb, const float* __restrict__ bnb,
                            const float* __restrict__ waa,
                            float* __restrict__ u, float* __restrict__ v,
                            float* __restrict__ c0, float* __restrict__ c1,
                            ushort* __restrict__ WB) {
    __shared__ float redU[2], redV[2], redC0[2], redC1[2];
    const int i = blockIdx.x, e = threadIdx.x;
    const int lane = e & 63, wv = e >> 6;
    float wnb_ie = Wnb[i * D + e];
    WB[e * D + i] = f2bf(wnb_ie);
    float pu = Wmol[i * D + e] * wam[e];
    float pv = wnb_ie * waa[e];
    float q0 = (i == 0) ? bmol[e] * wam[e] : 0.f;
    float q1 = (i == 0) ? bnb[e] * waa[e] : 0.f;
    #pragma unroll
    for (int o = 1; o < 64; o <<= 1) {
        pu += __shfl_xor(pu, o); pv += __shfl_xor(pv, o);
        q0 += __shfl_xor(q0, o); q1 += __shfl_xor(q1, o);
    }
    if (lane == 0) { redU[wv] = pu; redV[wv] = pv; redC0[wv] = q0; redC1[wv] = q1; }
    __syncthreads();
    if (e == 0) {
        u[i] = redU[0] + redU[1];
        v[i] = redV[0] + redV[1];
        if (i == 0) { c0[0] = redC0[0] + redC0[1] + bal[0];
                      c1[0] = redC1[0] + redC1[1]; }
    }
}

// ---------------------------------------------------------------------------
// trans: atom fp32 -> atomT bf16 [b][d][l] + masked s_atm
// ---------------------------------------------------------------------------
__global__ __launch_bounds__(256) void trans_kernel(
    const float* __restrict__ atom, const float* __restrict__ v,
    const float* __restrict__ c1p, const float* __restrict__ smask,
    ushort* __restrict__ atomT, float* __restrict__ sM) {
    __shared__ ushort Ls[64][132];
    const int tid = threadIdx.x;
    const int q = tid & 31, rg = tid >> 5;
    const int bidx = blockIdx.x;
    const int x = bidx & 7, j = bidx >> 3;
    const int b = x + 8 * (j & 7);
    const int l0 = (j >> 3) * 64;
    const float4 vq = *(const float4*)&v[q * 4];
    const float c1 = c1p[0];

    #pragma unroll
    for (int k = 0; k < 8; ++k) {
        const int l = rg * 8 + k;
        float4 xv = *(const float4*)&atom[((size_t)b * L + l0 + l) * D + q * 4];
        float dot = xv.x * vq.x + xv.y * vq.y + xv.z * vq.z + xv.w * vq.w;
        dot += __shfl_xor(dot, 1);  dot += __shfl_xor(dot, 2);
        dot += __shfl_xor(dot, 4);  dot += __shfl_xor(dot, 8);
        dot += __shfl_xor(dot, 16);
        union { ushort us[4]; uint2 u2; } pk;
        pk.us[0] = f2bf(xv.x); pk.us[1] = f2bf(xv.y);
        pk.us[2] = f2bf(xv.z); pk.us[3] = f2bf(xv.w);
        *(uint2*)&Ls[l][q * 4] = pk.u2;
        if (q == 0) {
            float msk = smask[(size_t)b * L + l0 + l];
            sM[(size_t)b * L + l0 + l] = (msk > -0.5f) ? (dot + c1) : -1e30f;
        }
    }
    __syncthreads();
    {
        const int d = tid >> 1, h = tid & 1;
        #pragma unroll
        for (int jj = 0; jj < 4; ++jj) {
            alignas(16) ushort tmp[8];
            #pragma unroll
            for (int m = 0; m < 8; ++m) tmp[m] = Ls[h * 32 + jj * 8 + m][d];
            *(int4*)&atomT[((size_t)(b * 128 + d) << 10) + l0 + h * 32 + jj * 8] =
                *(int4*)tmp;
        }
    }
}

// ---------------------------------------------------------------------------
// attn v11: block = (b, 32 a-rows), 4 waves, mfma_32x32x16.
// Wave w owns K-chunks (16 l) c in {w, w+4} of every 128-l tile.
// Tiles staged via global_load_lds(16B) into XOR-swizzled arena, dbuf.
// K-partials combined via fp32 LDS exchange (overlaid on dead tiles);
// epilogue (TT bounce + ctx=W.T GEMM + LayerNorm) is the R9-verified code.
// ---------------------------------------------------------------------------
__global__ __launch_bounds__(256, 2) void attn_kernel(
    const float* __restrict__ molf, const float* __restrict__ amask,
    const ushort* __restrict__ atomT, const float* __restrict__ sM_g,
    const float* __restrict__ u, const float* __restrict__ c0p,
    const ushort* __restrict__ WB, const float* __restrict__ bnb,
    const float* __restrict__ gamma, const float* __restrict__ beta,
    float* __restrict__ out) {
    __shared__ __align__(16) char arena[65536];          // tiles / cbuf / TT
    __shared__ __align__(16) ushort sLb[1024], eLb[1024], fLb[1024];
    __shared__ float thL[32], eaL[32], faL[32];
    __shared__ float wmaxL[4];
    __shared__ float psW[4][32];
    __shared__ float lnP[4][2][16][2];
    __shared__ float gbL[256];

    const int bid = blockIdx.x;
    const int lid = (bid & 7) * 64 + (bid >> 3);   // XCD-bijective (512 % 8 == 0)
    const int b  = lid >> 3;
    const int at = lid & 7;
    const int tid = threadIdx.x;
    const int w = tid >> 6, lane = tid & 63;
    const int la = lane & 15, kg = lane >> 4;
    const int al = lane & 31, hi = lane >> 5;
    const int xo = la & 7;

    const ushort* atomTb = atomT + (size_t)b * D * L;

    // stage: 8 x global_load_lds(16B) per wave; wave-uniform LDS dest,
    // per-lane pre-swizzled global source (stored[r][s] = logical[s^(r&15)])
#define STAGE(BUFOFF_, T_)                                                     \
    {                                                                          \
        _Pragma("unroll")                                                      \
        for (int q_ = 0; q_ < 8; ++q_) {                                       \
            const int rbase_ = w * 32 + q_ * 4;                                \
            const int rr_ = rbase_ + (lane >> 4);                              \
            const ushort* g_ = atomTb + (size_t)rr_ * L + (T_) * 128           \
                               + (((lane & 15) ^ (rr_ & 15)) << 3);            \
            gl_lds16(g_, arena + (BUFOFF_) + rbase_ * 256);                    \
        }                                                                      \
    }

    STAGE(0, 0)   // tile 0 DMA flies under phases A0/B

    if (tid < 32)      ((float4*)gbL)[tid] = ((const float4*)gamma)[tid];
    else if (tid < 64) ((float4*)gbL)[tid] = ((const float4*)beta)[tid - 32];

    // ---- phase A0: softmax tables (bf16) + batch max
    {
        const int i4 = tid * 4;
        float4 sa = *(const float4*)&sM_g[(size_t)b * L + i4];
        union { ushort us[4]; uint2 u2; } ps, pe, pf;
        ps.us[0] = f2bf(sa.x); ps.us[1] = f2bf(sa.y);
        ps.us[2] = f2bf(sa.z); ps.us[3] = f2bf(sa.w);
        pe.us[0] = f2bf(__expf(sa.x)); pe.us[1] = f2bf(__expf(sa.y));
        pe.us[2] = f2bf(__expf(sa.z)); pe.us[3] = f2bf(__expf(sa.w));
        pf.us[0] = f2bf(__expf(NEG_SLOPE * sa.x)); pf.us[1] = f2bf(__expf(NEG_SLOPE * sa.y));
        pf.us[2] = f2bf(__expf(NEG_SLOPE * sa.z)); pf.us[3] = f2bf(__expf(NEG_SLOPE * sa.w));
        *(uint2*)&sLb[i4] = ps.u2; *(uint2*)&eLb[i4] = pe.u2; *(uint2*)&fLb[i4] = pf.u2;
        float mx = fmaxf(fmaxf(sa.x, sa.y), fmaxf(sa.z, sa.w));
        #pragma unroll
        for (int o = 1; o < 64; o <<= 1) mx = fmaxf(mx, __shfl_xor(mx, o));
        if (lane == 0) wmaxL[w] = mx;
    }
    __syncthreads();

    // ---- phase B: s_mol + per-row softmax constants (32 rows x 8 threads)
    {
        const float M = fmaxf(fmaxf(wmaxL[0], wmaxL[1]), fmaxf(wmaxL[2], wmaxL[3]));
        const int r = tid >> 3, q = tid & 7;
        const float* xp = molf + ((size_t)b * A + at * 32 + r) * D + q * 16;
        float p = 0.f;
        #pragma unroll
        for (int k = 0; k < 4; ++k) {
            float4 xv = *(const float4*)&xp[k * 4];
            float4 uv = *(const float4*)&u[q * 16 + k * 4];
            p += xv.x * uv.x + xv.y * uv.y + xv.z * uv.z + xv.w * uv.w;
        }
        p += __shfl_xor(p, 1); p += __shfl_xor(p, 2); p += __shfl_xor(p, 4);
        if (q == 0) {
            float sm = p + c0p[0];
            float z = sm + M;
            float m = (z > 0.f) ? z : NEG_SLOPE * z;
            thL[r] = -sm;
            eaL[r] = __expf(sm - m);
            faL[r] = __expf(NEG_SLOPE * sm - m);
        }
    }
    __syncthreads();   // tile 0 staged (vmcnt drained) + consts ready

    const float thW = thL[al], eaW = eaL[al], faW = faL[al];
    f32x16 acc[4] = {};
    float psum = 0.f;

#define COMPUTE(BUFOFF_, T_)                                                   \
    {                                                                          \
        _Pragma("unroll")                                                      \
        for (int ci_ = 0; ci_ < 2; ++ci_) {                                    \
            const int c_ = w + ci_ * 4;                                        \
            const int lb_ = (T_) * 128 + c_ * 16 + hi * 8;                     \
            bf16x8 sb = *(const bf16x8*)&sLb[lb_];                             \
            bf16x8 eb = *(const bf16x8*)&eLb[lb_];                             \
            bf16x8 fb = *(const bf16x8*)&fLb[lb_];                             \
            bf16x8 bfrag;                                                      \
            _Pragma("unroll")                                                  \
            for (int j_ = 0; j_ < 8; ++j_) {                                   \
                float s_ = bf2f((ushort)sb[j_]);                               \
                float e_ = bf2f((ushort)eb[j_]);                               \
                float f_ = bf2f((ushort)fb[j_]);                               \
                float p_ = (s_ > thW) ? eaW * e_ : faW * f_;                   \
                psum += p_;                                                    \
                bfrag[j_] = (short)f2bf(p_);                                   \
            }                                                                  \
            const int lch_ = c_ * 2 + hi;                                      \
            _Pragma("unroll")                                                  \
            for (int dt_ = 0; dt_ < 4; ++dt_) {                                \
                const int row_ = dt_ * 32 + al;                                \
                bf16x8 af = *(const bf16x8*)(arena + (BUFOFF_) + row_ * 256    \
                                             + ((lch_ ^ (row_ & 15)) << 4));   \
                acc[dt_] = __builtin_amdgcn_mfma_f32_32x32x16_bf16(            \
                    af, bfrag, acc[dt_], 0, 0, 0);                             \
            }                                                                  \
        }                                                                      \
    }

    STAGE(32768, 1) COMPUTE(0, 0)     __syncthreads();
    STAGE(0, 2)     COMPUTE(32768, 1) __syncthreads();
    STAGE(32768, 3) COMPUTE(0, 2)     __syncthreads();
    STAGE(0, 4)     COMPUTE(32768, 3) __syncthreads();
    STAGE(32768, 5) COMPUTE(0, 4)     __syncthreads();
    STAGE(0, 6)     COMPUTE(32768, 5) __syncthreads();
    STAGE(32768, 7) COMPUTE(0, 6)     __syncthreads();
    COMPUTE(32768, 7)
#undef COMPUTE
#undef STAGE

    // prefetch phase-F operands while waves drain
    bf16x8 wb0[4], wb1[4];
    {
        const ushort* wr0 = WB + (size_t)((2 * w) * 16 + la) * D + kg * 8;
        const ushort* wr1 = WB + (size_t)((2 * w + 1) * 16 + la) * D + kg * 8;
        #pragma unroll
        for (int ks = 0; ks < 4; ++ks) {
            wb0[ks] = *(const bf16x8*)&wr0[ks * 32];
            wb1[ks] = *(const bf16x8*)&wr1[ks * 32];
        }
    }
    float4 bias0 = *(const float4*)&bnb[w * 32 + kg * 4];
    float4 bias1 = *(const float4*)&bnb[w * 32 + 16 + kg * 4];
    const float amA = amask[(size_t)b * A + at * 32 + la];
    const float amB = amask[(size_t)b * A + at * 32 + 16 + la];

    // psum: lanes l and l+32 share a
    psum += __shfl_xor(psum, 32);
    __syncthreads();                 // all tile reads done -> cbuf overlay safe
    if (lane < 32) psW[w][al] = psum;

    // ---- K-combine step 1: acc -> cbuf[w] (fp32, float4-slot XOR swizzle)
    {
        char* cb = arena + w * 16384;   // [32 a][32 slots of 16B]
        #pragma unroll
        for (int dt_ = 0; dt_ < 4; ++dt_) {
            #pragma unroll
            for (int q_ = 0; q_ < 4; ++q_) {
                float4 v4;
                v4.x = acc[dt_][q_ * 4 + 0]; v4.y = acc[dt_][q_ * 4 + 1];
                v4.z = acc[dt_][q_ * 4 + 2]; v4.w = acc[dt_][q_ * 4 + 3];
                const int s_ = dt_ * 8 + q_ * 2 + hi;   // d = 4*s
                *(float4*)(cb + al * 512 + ((s_ ^ al) << 4)) = v4;
            }
        }
    }
    __syncthreads();

    // ---- K-combine step 2: sum 4 planes into registers (thread = a, 16 d)
    float t16[16];
    {
        const int a_ = tid >> 3, dc = tid & 7;
        #pragma unroll
        for (int i = 0; i < 16; ++i) t16[i] = 0.f;
        #pragma unroll
        for (int w_ = 0; w_ < 4; ++w_) {
            const char* cb = arena + w_ * 16384 + a_ * 512;
            #pragma unroll
            for (int sj = 0; sj < 4; ++sj) {
                float4 v = *(const float4*)(cb + (((dc * 4 + sj) ^ a_) << 4));
                t16[sj * 4 + 0] += v.x; t16[sj * 4 + 1] += v.y;
                t16[sj * 4 + 2] += v.z; t16[sj * 4 + 3] += v.w;
            }
        }
    }
    __syncthreads();                 // cbuf reads done -> TT overlay safe

    // ---- write TT[32][128] bf16 (chunk-XOR) at arena base
    {
        const int a_ = tid >> 3, dc = tid & 7;
        #pragma unroll
        for (int h = 0; h < 2; ++h) {
            union { ushort us[8]; int4 v; } pk;
            #pragma unroll
            for (int i = 0; i < 8; ++i) pk.us[i] = f2bf(t16[h * 8 + i]);
            const int cc = dc * 2 + h;
            *(int4*)(arena + a_ * 256 + ((cc ^ (a_ & 7)) << 4)) = pk.v;
        }
    }
    __syncthreads();

    // ---- phase F: ctx = T.W (16 MFMA/wave) + LayerNorm  (R9-verified)
    const char* TT = arena;
#define LDT(ROW_, KS_) (*(const bf16x8*)(TT + (ROW_) * 256 + \
                         ((((KS_) * 4 + kg) ^ xo) << 4)))
    f32x4 cA0 = {}, cA1 = {}, cB0 = {}, cB1 = {};
    #pragma unroll
    for (int ks = 0; ks < 4; ++ks) {
        bf16x8 tA = LDT(la, ks);
        bf16x8 tB = LDT(la + 16, ks);
        cA0 = __builtin_amdgcn_mfma_f32_16x16x32_bf16(wb0[ks], tA, cA0, 0, 0, 0);
        cA1 = __builtin_amdgcn_mfma_f32_16x16x32_bf16(wb1[ks], tA, cA1, 0, 0, 0);
        cB0 = __builtin_amdgcn_mfma_f32_16x16x32_bf16(wb0[ks], tB, cB0, 0, 0, 0);
        cB1 = __builtin_amdgcn_mfma_f32_16x16x32_bf16(wb1[ks], tB, cB1, 0, 0, 0);
    }
#undef LDT

    const float psA = psW[0][la] + psW[1][la] + psW[2][la] + psW[3][la];
    const float psB = psW[0][la + 16] + psW[1][la + 16]
                    + psW[2][la + 16] + psW[3][la + 16];
    const float scA = amA / psA, scB = amB / psB;
    float xA[8], xB[8];
    float s1A = 0.f, s2A = 0.f, s1B = 0.f, s2B = 0.f;
    const float* bp0 = (const float*)&bias0;
    const float* bp1 = (const float*)&bias1;
    #pragma unroll
    for (int r = 0; r < 4; ++r) {
        xA[r]     = cA0[r] * scA + amA * bp0[r];
        xA[4 + r] = cA1[r] * scA + amA * bp1[r];
        xB[r]     = cB0[r] * scB + amB * bp0[r];
        xB[4 + r] = cB1[r] * scB + amB * bp1[r];
        s1A += xA[r] + xA[4 + r]; s2A += xA[r] * xA[r] + xA[4 + r] * xA[4 + r];
        s1B += xB[r] + xB[4 + r]; s2B += xB[r] * xB[r] + xB[4 + r] * xB[4 + r];
    }
    s1A += __shfl_xor(s1A, 16); s1A += __shfl_xor(s1A, 32);
    s2A += __shfl_xor(s2A, 16); s2A += __shfl_xor(s2A, 32);
    s1B += __shfl_xor(s1B, 16); s1B += __shfl_xor(s1B, 32);
    s2B += __shfl_xor(s2B, 16); s2B += __shfl_xor(s2B, 32);
    if (lane < 16) {
        lnP[w][0][la][0] = s1A; lnP[w][0][la][1] = s2A;
        lnP[w][1][la][0] = s1B; lnP[w][1][la][1] = s2B;
    }
    __syncthreads();
    const float S1A = lnP[0][0][la][0] + lnP[1][0][la][0] + lnP[2][0][la][0] + lnP[3][0][la][0];
    const float S2A = lnP[0][0][la][1] + lnP[1][0][la][1] + lnP[2][0][la][1] + lnP[3][0][la][1];
    const float S1B = lnP[0][1][la][0] + lnP[1][1][la][0] + lnP[2][1][la][0] + lnP[3][1][la][0];
    const float S2B = lnP[0][1][la][1] + lnP[1][1][la][1] + lnP[2][1][la][1] + lnP[3][1][la][1];
    const float muA = S1A * (1.f / 128.f);
    const float rsA = rsqrtf(S2A * (1.f / 128.f) - muA * muA + LN_EPS);
    const float muB = S1B * (1.f / 128.f);
    const float rsB = rsqrtf(S2B * (1.f / 128.f) - muB * muB + LN_EPS);
    const size_t oA = ((size_t)b * A + at * 32 + la) * D;
    const size_t oB = ((size_t)b * A + at * 32 + 16 + la) * D;
    #pragma unroll
    for (int t = 0; t < 2; ++t) {
        const int e0 = w * 32 + t * 16 + kg * 4;
        float4 g4 = *(float4*)&gbL[e0];
        float4 b4 = *(float4*)&gbL[128 + e0];
        float4 ovA, ovB;
        const float* xpA = &xA[t * 4];
        const float* xpB = &xB[t * 4];
        ((float*)&ovA)[0] = (xpA[0] - muA) * rsA * g4.x + b4.x;
        ((float*)&ovA)[1] = (xpA[1] - muA) * rsA * g4.y + b4.y;
        ((float*)&ovA)[2] = (xpA[2] - muA) * rsA * g4.z + b4.z;
        ((float*)&ovA)[3] = (xpA[3] - muA) * rsA * g4.w + b4.w;
        ((float*)&ovB)[0] = (xpB[0] - muB) * rsB * g4.x + b4.x;
        ((float*)&ovB)[1] = (xpB[1] - muB) * rsB * g4.y + b4.y;
        ((float*)&ovB)[2] = (xpB[2] - muB) * rsB * g4.z + b4.z;
        ((float*)&ovB)[3] = (xpB[3] - muB) * rsB * g4.w + b4.w;
        *(float4*)&out[oA + e0] = ovA;
        *(float4*)&out[oB + e0] = ovB;
    }
}

// ---------------------------------------------------------------------------
extern "C" void kernel_launch(void* const* d_in, const int* in_sizes, int n_in,
                              void* d_out, int out_size, void* d_ws, size_t ws_size,
                              hipStream_t stream) {
    const float* molf  = (const float*)d_in[0];
    const float* atomf = (const float*)d_in[1];
    const float* amask = (const float*)d_in[2];
    const float* smask = (const float*)d_in[3];
    const float* W_mol = (const float*)d_in[4];
    const float* b_mol = (const float*)d_in[5];
    const float* W_nb  = (const float*)d_in[6];
    const float* b_nb  = (const float*)d_in[7];
    const float* w_am  = (const float*)d_in[8];
    const float* w_aa  = (const float*)d_in[9];
    const float* b_al  = (const float*)d_in[10];
    const float* gamma = (const float*)d_in[11];
    const float* beta  = (const float*)d_in[12];
    float* out = (float*)d_out;

    // ws: atomT bf16 [B*D*L] | sM [B*L] | u,v [D] | c0,c1 | WB bf16 [D*D]
    ushort* atomT = (ushort*)d_ws;
    float* sM     = (float*)(atomT + (size_t)B * D * L);
    float* u_ws   = sM + (size_t)B * L;
    float* v_ws   = u_ws + D;
    float* c0_ws  = v_ws + D;
    float* c1_ws  = c0_ws + 1;
    ushort* WB    = (ushort*)(c1_ws + 1);

    prep_kernel<<<128, 128, 0, stream>>>(W_mol, b_mol, w_am, b_al, W_nb, b_nb,
                                         w_aa, u_ws, v_ws, c0_ws, c1_ws, WB);
    trans_kernel<<<(B * L) / 64, 256, 0, stream>>>(atomf, v_ws, c1_ws, smask,
                                                   atomT, sM);
    attn_kernel<<<B * (A / 32), 256, 0, stream>>>(molf, amask, atomT, sM, u_ws,
                                                  c0_ws, WB, b_nb, gamma, beta, out);
}